// Round 14
// baseline (669.790 us; speedup 1.0000x reference)
//
#include <hip/hip_runtime.h>
#include <hip/hip_bf16.h>
#include <math.h>

// ---------------------------------------------------------------------------
// BasicTransformer block on MI355X, bf16-MFMA implementation.
// B=2 S=2048 H=2048 NH=32 HD=64 FFN=8192
// R14: ALL four GEMMs on the R13 3-deep buffer rotation (gemm3b, BM=128):
// whole-tile staging at tile top, 1 barrier + 1 counted vmcnt(6)/K-tile,
// no intra-tile sync. FFN1 moves from gemm8p BM=256 to gemm3b grid(32,32).
// ---------------------------------------------------------------------------

typedef __attribute__((ext_vector_type(8))) short bf16x8;
typedef __attribute__((ext_vector_type(4))) float f32x4;
typedef __attribute__((ext_vector_type(16))) float f32x16;

#define DEV __device__ __forceinline__

static constexpr int SEQ  = 2048;
static constexpr int HID  = 2048;
static constexpr int NHEAD = 32;
static constexpr int HDIM = 64;
static constexpr int NFFN = 8192;
static constexpr int NTOK = 2 * SEQ;       // 4096 rows
static constexpr int QKVW = 3 * HID;       // 6144

// 0.125 (1/sqrt(64)) * log2(e): folded into Q so P = exp2(S - m)
#define QSCALE 0.1803368801111204f

#if defined(__has_builtin)
#if __has_builtin(__builtin_amdgcn_exp2f)
#define EXP2(x) __builtin_amdgcn_exp2f(x)
#endif
#endif
#ifndef EXP2
#define EXP2(x) exp2f(x)
#endif

#define VMCNT(n) asm volatile("s_waitcnt vmcnt(" #n ")" ::: "memory")
#define SB0()    __builtin_amdgcn_sched_barrier(0)

DEV ushort f2bf(float f) {                 // RNE f32 -> bf16
  unsigned u = __float_as_uint(f);
  return (ushort)((u + 0x7fffu + ((u >> 16) & 1u)) >> 16);
}

DEV void gload16(const void* g, void* l) { // async global->LDS, 16B/lane
  __builtin_amdgcn_global_load_lds(
      (const __attribute__((address_space(1))) unsigned int*)g,
      (__attribute__((address_space(3))) unsigned int*)l, 16, 0, 0);
}

// ---------------------------------------------------------------------------
// transpose + convert: in [R][C] f32  ->  out [C][R] bf16
// ---------------------------------------------------------------------------
__global__ __launch_bounds__(256) void tcvt_kernel(const float* __restrict__ in,
                                                   ushort* __restrict__ out,
                                                   int R, int C) {
  __shared__ ushort tile[64][72];
  const int tr = blockIdx.y * 64, tc = blockIdx.x * 64;
  const int t = threadIdx.x;
  const int rr = t >> 2, c4 = (t & 3) * 16;
  const float4* ip = (const float4*)(in + (size_t)(tr + rr) * C + tc + c4);
  float4 a0 = ip[0], a1 = ip[1], a2 = ip[2], a3 = ip[3];
  ushort* tp = &tile[rr][c4];
  tp[0]=f2bf(a0.x); tp[1]=f2bf(a0.y); tp[2]=f2bf(a0.z); tp[3]=f2bf(a0.w);
  tp[4]=f2bf(a1.x); tp[5]=f2bf(a1.y); tp[6]=f2bf(a1.z); tp[7]=f2bf(a1.w);
  tp[8]=f2bf(a2.x); tp[9]=f2bf(a2.y); tp[10]=f2bf(a2.z); tp[11]=f2bf(a2.w);
  tp[12]=f2bf(a3.x); tp[13]=f2bf(a3.y); tp[14]=f2bf(a3.z); tp[15]=f2bf(a3.w);
  __syncthreads();
  union { ushort u[8]; bf16x8 v; } p0, p1;
#pragma unroll
  for (int j = 0; j < 8; ++j) { p0.u[j] = tile[c4 + j][rr]; p1.u[j] = tile[c4 + 8 + j][rr]; }
  ushort* op = out + (size_t)(tc + rr) * R + tr + c4;
  *(bf16x8*)op = p0.v;
  *(bf16x8*)(op + 8) = p1.v;
}

// ---------------------------------------------------------------------------
// LayerNorm row kernel: x [rows][2048] f32 -> out bf16
// ---------------------------------------------------------------------------
__global__ __launch_bounds__(256) void ln_kernel(const float* __restrict__ x,
                                                 const float* __restrict__ g,
                                                 const float* __restrict__ bb,
                                                 ushort* __restrict__ out) {
  const int row = blockIdx.x, t = threadIdx.x;
  const float4* xv = (const float4*)(x + (size_t)row * HID);
  float4 a0 = xv[t * 2], a1 = xv[t * 2 + 1];
  float s  = a0.x + a0.y + a0.z + a0.w + a1.x + a1.y + a1.z + a1.w;
  float ss = a0.x*a0.x + a0.y*a0.y + a0.z*a0.z + a0.w*a0.w
           + a1.x*a1.x + a1.y*a1.y + a1.z*a1.z + a1.w*a1.w;
#pragma unroll
  for (int o = 32; o > 0; o >>= 1) { s += __shfl_down(s, o); ss += __shfl_down(ss, o); }
  __shared__ float red[8];
  const int w = t >> 6, l = t & 63;
  if (l == 0) { red[w] = s; red[4 + w] = ss; }
  __syncthreads();
  s  = red[0] + red[1] + red[2] + red[3];
  ss = red[4] + red[5] + red[6] + red[7];
  const float mu = s * (1.f / HID);
  const float rs = rsqrtf(ss * (1.f / HID) - mu * mu + 1e-5f);
  const float4* gv = (const float4*)g;
  const float4* bv = (const float4*)bb;
  float4 g0 = gv[t * 2], g1 = gv[t * 2 + 1], b0 = bv[t * 2], b1 = bv[t * 2 + 1];
  union { ushort u[8]; bf16x8 v; } p;
  p.u[0] = f2bf((a0.x - mu) * rs * g0.x + b0.x);
  p.u[1] = f2bf((a0.y - mu) * rs * g0.y + b0.y);
  p.u[2] = f2bf((a0.z - mu) * rs * g0.z + b0.z);
  p.u[3] = f2bf((a0.w - mu) * rs * g0.w + b0.w);
  p.u[4] = f2bf((a1.x - mu) * rs * g1.x + b1.x);
  p.u[5] = f2bf((a1.y - mu) * rs * g1.y + b1.y);
  p.u[6] = f2bf((a1.z - mu) * rs * g1.z + b1.z);
  p.u[7] = f2bf((a1.w - mu) * rs * g1.w + b1.w);
  *(bf16x8*)(out + (size_t)row * HID + t * 8) = p.v;
}

// ---------------------------------------------------------------------------
// QKV fragment-packed store (layout the attn kernel consumes).
// ---------------------------------------------------------------------------
DEV void qkv_store(int row, int col, float v,
                   ushort* __restrict__ qpk, ushort* __restrict__ kpk,
                   ushort* __restrict__ vpk) {
  const int h = col / 192;
  const int c = col - h * 192;
  const int bh2 = (row >> 11) * 32 + h;
  const int t32 = (row >> 5) & 63;
  const int r5 = row & 31;
  if (c < 64) {
    const int s = c >> 4, hi2 = (c >> 3) & 1, j = c & 7;
    qpk[(((size_t)bh2 * 64 + t32) * 4 + s) * 512 + (hi2 * 32 + r5) * 8 + j] = f2bf(v * QSCALE);
  } else if (c < 128) {
    const int d = c - 64;
    const int s = d >> 4, hi2 = (d >> 3) & 1, j = d & 7;
    kpk[(((size_t)bh2 * 64 + t32) * 4 + s) * 512 + (hi2 * 32 + r5) * 8 + j] = f2bf(v);
  } else {
    const int d = c - 128;
    const int ks = r5 >> 4, hi2 = (r5 >> 3) & 1, j = r5 & 7;
    const int half = d >> 5, dl = d & 31;
    vpk[((((size_t)bh2 * 64 + t32) * 2 + ks) * 2 + half) * 512 + (hi2 * 32 + dl) * 8 + j] = f2bf(v);
  }
}

// ---------------------------------------------------------------------------
// R13 3-deep buffer rotation GEMM, BM=128, BN=256, BK=64, 512 thr.
// Whole-tile stage at tile top; one lgkm(0)+vmcnt(6)+barrier per K-tile;
// fragment reads + 32 MFMAs compiler-scheduled (no intra-tile sync).
// EPI 1: +bias+res->f32   2: +bias,gelu->bf16   3: QKV fragment-pack
// ---------------------------------------------------------------------------
#define G3BODY(CB, SB)                                                         \
  {                                                                            \
    const bool s2_ = (tt + 2) < nt;                                            \
    if (s2_) {                                                                 \
      const int k2_ = (tt + 2) << 6;                                           \
      gload16(ga0 + k2_, Ab##SB + da0); gload16(ga1 + k2_, Ab##SB + da1);      \
      gload16(gb0 + k2_, Bb##SB + db0); gload16(gb1 + k2_, Bb##SB + db1);      \
      gload16(gb2 + k2_, Bb##SB + db2); gload16(gb3 + k2_, Bb##SB + db3);      \
    }                                                                          \
    bf16x8 af_[4][2], bf_[4][2];                                               \
    _Pragma("unroll") for (int mf = 0; mf < 4; ++mf) {                         \
      af_[mf][0] = *(const bf16x8*)(pA##CB##0 + mf * 2048);                    \
      af_[mf][1] = *(const bf16x8*)(pA##CB##1 + mf * 2048);                    \
    }                                                                          \
    _Pragma("unroll") for (int nf = 0; nf < 4; ++nf) {                         \
      bf_[nf][0] = *(const bf16x8*)(pB##CB##0 + nf * 2048);                    \
      bf_[nf][1] = *(const bf16x8*)(pB##CB##1 + nf * 2048);                    \
    }                                                                          \
    __builtin_amdgcn_s_setprio(1);                                             \
    _Pragma("unroll") for (int mf = 0; mf < 4; ++mf)                           \
      _Pragma("unroll") for (int nf = 0; nf < 4; ++nf)                         \
        _Pragma("unroll") for (int ks = 0; ks < 2; ++ks)                       \
          acc[mf][nf] = __builtin_amdgcn_mfma_f32_16x16x32_bf16(               \
              af_[mf][ks], bf_[nf][ks], acc[mf][nf], 0, 0, 0);                 \
    __builtin_amdgcn_s_setprio(0);                                             \
    asm volatile("s_waitcnt lgkmcnt(0)" ::: "memory");                         \
    if (s2_) { VMCNT(6); }                                                     \
    else if (tt + 1 < nt) { VMCNT(0); }                                        \
    __builtin_amdgcn_s_barrier();                                              \
  }

template <int EPI>
__global__ __launch_bounds__(512, 2) void gemm3b_kernel(
    const ushort* __restrict__ A, const ushort* __restrict__ BT,
    const float* __restrict__ bias, const float* __restrict__ res,
    void* __restrict__ outv,
    ushort* __restrict__ qpk, ushort* __restrict__ kpk, ushort* __restrict__ vpk,
    int M, int N, int K) {
  __shared__ ushort lds[73728];              // 144 KiB = 3 x (16KB A + 32KB B)
  char* const L = (char*)lds;
  char* const Ab0 = L;             char* const Bb0 = L + 16384;
  char* const Ab1 = L + 49152;     char* const Bb1 = Ab1 + 16384;
  char* const Ab2 = L + 98304;     char* const Bb2 = Ab2 + 16384;

  const int t = threadIdx.x;
  const int w = t >> 6, l = t & 63;
  const int l16 = l & 15, lg = l >> 4, lr = l >> 3, lsl = l & 7, l7 = l & 7;
  const int wm = w >> 2, wn = w & 3;

  const int nwg = gridDim.x * gridDim.y;
  const int lin = blockIdx.y * gridDim.x + blockIdx.x;
  const int work = (lin & 7) * (nwg >> 3) + (lin >> 3);
  const int bn = work % gridDim.x, bm = work / gridDim.x;
  const int tm = bm * 128, tn = bn * 256;

  // fragment read bases (swizzle folded: row&7 == l&7 for all frag rows)
  const int xk0 = (lg ^ l7) << 4, xk1 = ((4 + lg) ^ l7) << 4;
  const int aoff = (wm * 64 + l16) * 128;
  const int boff = (wn * 64 + l16) * 128;
  const char* pA00 = Ab0 + aoff + xk0;  const char* pA01 = Ab0 + aoff + xk1;
  const char* pA10 = Ab1 + aoff + xk0;  const char* pA11 = Ab1 + aoff + xk1;
  const char* pA20 = Ab2 + aoff + xk0;  const char* pA21 = Ab2 + aoff + xk1;
  const char* pB00 = Bb0 + boff + xk0;  const char* pB01 = Bb0 + boff + xk1;
  const char* pB10 = Bb1 + boff + xk0;  const char* pB11 = Bb1 + boff + xk1;
  const char* pB20 = Bb2 + boff + xk0;  const char* pB21 = Bb2 + boff + xk1;

  // stage pointers (6 loads/tile) + dest offsets (inverse-swizzled source)
  const int ri = w * 8 + lr;
  const int rA0 = (ri >> 5) * 64 + (ri & 31);
  const int rA1 = rA0 + 32;
  const int ri2 = 64 + ri;
  const int rB0 = rA0;
  const int rB1 = (ri2 >> 5) * 64 + (ri2 & 31);
  const int rB2 = rB0 + 32;
  const int rB3 = rB1 + 32;
  const int gcol = (lsl ^ lr) << 3;
  const ushort* ga0 = A + (size_t)(tm + rA0) * K + gcol;
  const ushort* ga1 = A + (size_t)(tm + rA1) * K + gcol;
  const ushort* gb0 = BT + (size_t)(tn + rB0) * K + gcol;
  const ushort* gb1 = BT + (size_t)(tn + rB1) * K + gcol;
  const ushort* gb2 = BT + (size_t)(tn + rB2) * K + gcol;
  const ushort* gb3 = BT + (size_t)(tn + rB3) * K + gcol;
  const int da0 = rA0 * 128 + lsl * 16, da1 = rA1 * 128 + lsl * 16;
  const int db0 = rB0 * 128 + lsl * 16, db1 = rB1 * 128 + lsl * 16;
  const int db2 = rB2 * 128 + lsl * 16, db3 = rB3 * 128 + lsl * 16;

  const f32x4 z4 = {0.f, 0.f, 0.f, 0.f};
  f32x4 acc[4][4];
#pragma unroll
  for (int i = 0; i < 4; ++i)
#pragma unroll
    for (int j = 0; j < 4; ++j) acc[i][j] = z4;

  const int nt = K >> 6;                 // >= 3 for all our shapes

  // prologue: stage tile0 -> buf0, tile1 -> buf1; drain tile0; barrier.
  gload16(ga0, Ab0 + da0); gload16(ga1, Ab0 + da1);
  gload16(gb0, Bb0 + db0); gload16(gb1, Bb0 + db1);
  gload16(gb2, Bb0 + db2); gload16(gb3, Bb0 + db3);
  gload16(ga0 + 64, Ab1 + da0); gload16(ga1 + 64, Ab1 + da1);
  gload16(gb0 + 64, Bb1 + db0); gload16(gb1 + 64, Bb1 + db1);
  gload16(gb2 + 64, Bb1 + db2); gload16(gb3 + 64, Bb1 + db3);
  VMCNT(6);
  __builtin_amdgcn_s_barrier();

  int tt = 0;
  while (true) {
    G3BODY(0, 2); ++tt; if (tt >= nt) break;
    G3BODY(1, 0); ++tt; if (tt >= nt) break;
    G3BODY(2, 1); ++tt; if (tt >= nt) break;
  }

  // epilogue
  const int row0 = tm + wm * 64 + lg * 4;
  const int col0 = tn + wn * 64 + l16;
#pragma unroll
  for (int ni = 0; ni < 4; ++ni) {
    const int col = col0 + ni * 16;
    const float bvl = bias[col];
#pragma unroll
    for (int mi = 0; mi < 4; ++mi) {
#pragma unroll
      for (int r = 0; r < 4; ++r) {
        const int row = row0 + mi * 16 + r;
        float v = acc[mi][ni][r] + bvl;
        if (EPI == 1) {
          const size_t off = (size_t)row * N + col;
          ((float*)outv)[off] = v + res[off];
        } else if (EPI == 2) {
          const float u = 0.7978845608f * (v + 0.044715f * v * v * v);
          ((ushort*)outv)[(size_t)row * N + col] = f2bf(v / (1.f + __expf(-2.f * u)));
        } else if (EPI == 3) {
          qkv_store(row, col, v, qpk, kpk, vpk);
        } else {
          ((ushort*)outv)[(size_t)row * N + col] = f2bf(v);
        }
      }
    }
  }
}

// ---------------------------------------------------------------------------
// Flash attention: zero-LDS, all operands fragment-packed & coalesced.
// Grid (16,64). 4 indep waves/block, wave = 32 q rows, KV tile = 32.
// ---------------------------------------------------------------------------
__global__ __launch_bounds__(256) void attn_kernel(const ushort* __restrict__ qpk,
                                                   const ushort* __restrict__ kpk,
                                                   const ushort* __restrict__ vpk,
                                                   ushort* __restrict__ ctx) {
  const int lin = blockIdx.x + blockIdx.y * gridDim.x;
  const int work = (lin & 7) * 128 + (lin >> 3);
  const int qt = work & 15, bh = work >> 4;
  const int b = bh >> 5, h = bh & 31;
  const int t = threadIdx.x, w = t >> 6, l = t & 63;
  const int l32 = l & 31, hi = l >> 5;

  const ushort* qb = qpk + ((((size_t)bh * 64 + qt * 4 + w) * 4) * 64 + l) * 8;
  bf16x8 qf0 = *(const bf16x8*)(qb);
  bf16x8 qf1 = *(const bf16x8*)(qb + 512);
  bf16x8 qf2 = *(const bf16x8*)(qb + 1024);
  bf16x8 qf3 = *(const bf16x8*)(qb + 1536);

  const ushort* kbase = kpk + (size_t)bh * 131072 + l * 8;
  const ushort* vbase = vpk + (size_t)bh * 131072 + l * 8;

  f32x16 oacc0, oacc1;
#pragma unroll
  for (int r = 0; r < 16; ++r) { oacc0[r] = 0.f; oacc1[r] = 0.f; }
  float m = -1e30f, lsum = 0.f;
  const f32x16 z16 = {};

#define LOADK(k0, k1, k2, k3, kt) {                                           \
    const ushort* p_ = kbase + (size_t)(kt) * 2048;                           \
    k0 = *(const bf16x8*)(p_);        k1 = *(const bf16x8*)(p_ + 512);        \
    k2 = *(const bf16x8*)(p_ + 1024); k3 = *(const bf16x8*)(p_ + 1536); }
#define LOADV(v0, v1, v2, v3, kt) {                                           \
    const ushort* p_ = vbase + (size_t)(kt) * 2048;                           \
    v0 = *(const bf16x8*)(p_);        v1 = *(const bf16x8*)(p_ + 512);        \
    v2 = *(const bf16x8*)(p_ + 1024); v3 = *(const bf16x8*)(p_ + 1536); }

#define STEP(k0, k1, k2, k3, v0, v1, v2, v3) {                                \
    f32x16 s = __builtin_amdgcn_mfma_f32_32x32x16_bf16(k0, qf0, z16, 0, 0, 0);\
    s = __builtin_amdgcn_mfma_f32_32x32x16_bf16(k1, qf1, s, 0, 0, 0);         \
    s = __builtin_amdgcn_mfma_f32_32x32x16_bf16(k2, qf2, s, 0, 0, 0);         \
    s = __builtin_amdgcn_mfma_f32_32x32x16_bf16(k3, qf3, s, 0, 0, 0);         \
    float tm_ = s[0];                                                         \
    _Pragma("unroll") for (int r = 1; r < 16; ++r) tm_ = fmaxf(tm_, s[r]);    \
    tm_ = fmaxf(tm_, __shfl_xor(tm_, 32));                                    \
    if (!__all(tm_ - m <= 8.f)) {                                             \
      const float mn = fmaxf(m, tm_);                                         \
      const float sf = EXP2(m - mn);                                          \
      m = mn;                                                                 \
      lsum *= sf;                                                             \
      _Pragma("unroll") for (int r = 0; r < 16; ++r) {                        \
        const float f = __shfl(sf, (r & 3) + 8 * (r >> 2) + 4 * hi);          \
        oacc0[r] *= f; oacc1[r] *= f;                                         \
      }                                                                       \
    }                                                                         \
    float p[16];                                                              \
    _Pragma("unroll") for (int r = 0; r < 16; ++r) p[r] = EXP2(s[r] - m);     \
    float ls = 0.f;                                                           \
    _Pragma("unroll") for (int r = 0; r < 16; ++r) ls += p[r];                \
    lsum += ls;                                                               \
    unsigned pw[8];                                                           \
    _Pragma("unroll") for (int i = 0; i < 8; ++i)                             \
      asm("v_cvt_pk_bf16_f32 %0, %1, %2" : "=v"(pw[i]) : "v"(p[2*i]), "v"(p[2*i+1])); \
    unsigned a0 = pw[0], b0 = pw[2];                                          \
    asm("v_permlane32_swap_b32 %0, %1" : "+v"(a0), "+v"(b0));                 \
    unsigned a1 = pw[1], b1 = pw[3];                                          \
    asm("v_permlane32_swap_b32 %0, %1" : "+v"(a1), "+v"(b1));                 \
    unsigned a2 = pw[4], b2 = pw[6];                                          \
    asm("v_permlane32_swap_b32 %0, %1" : "+v"(a2), "+v"(b2));                 \
    unsigned a3 = pw[5], b3 = pw[7];                                          \
    asm("v_permlane32_swap_b32 %0, %1" : "+v"(a3), "+v"(b3));                 \
    union { unsigned uw[4]; bf16x8 v; } pa0, pa1;                             \
    pa0.uw[0] = a0; pa0.uw[1] = a1; pa0.uw[2] = b0; pa0.uw[3] = b1;           \
    pa1.uw[0] = a2; pa1.uw[1] = a3; pa1.uw[2] = b2; pa1.uw[3] = b3;           \
    oacc0 = __builtin_amdgcn_mfma_f32_32x32x16_bf16(pa0.v, v0, oacc0, 0, 0, 0);\
    oacc1 = __builtin_amdgcn_mfma_f32_32x32x16_bf16(pa0.v, v1, oacc1, 0, 0, 0);\
    oacc0 = __builtin_amdgcn_mfma_f32_32x32x16_bf16(pa1.v, v2, oacc0, 0, 0, 0);\
    oacc1 = __builtin_amdgcn_mfma_f32_32x32x16_bf16(pa1.v, v3, oacc1, 0, 0, 0);}

  bf16x8 ka0, ka1, ka2, ka3, kc0, kc1, kc2, kc3;
  LOADK(ka0, ka1, ka2, ka3, 0);
  for (int kt = 0; kt < 64; kt += 2) {
    bf16x8 va0, va1, va2, va3;
    LOADV(va0, va1, va2, va3, kt);
    LOADK(kc0, kc1, kc2, kc3, kt + 1);
    STEP(ka0, ka1, ka2, ka3, va0, va1, va2, va3);
    LOADV(va0, va1, va2, va3, kt + 1);
    if (kt + 2 < 64) LOADK(ka0, ka1, ka2, ka3, kt + 2);
    STEP(kc0, kc1, kc2, kc3, va0, va1, va2, va3);
  }
#undef LOADK
#undef LOADV
#undef STEP

  const float lf = lsum + __shfl_xor(lsum, 32);
  const float linv = 1.f / lf;
#pragma unroll
  for (int r = 0; r < 16; ++r) {
    const int qr = (r & 3) + 8 * (r >> 2);
    const float fac = __shfl(linv, qr + 4 * hi);
    const int row = qt * 128 + w * 32 + qr + 4 * hi;
    const size_t base = ((size_t)(b * SEQ + row)) * HID + h * 64 + l32;
    ctx[base]      = f2bf(oacc0[r] * fac);
    ctx[base + 32] = f2bf(oacc1[r] * fac);
  }
}

// ---------------------------------------------------------------------------
extern "C" void kernel_launch(void* const* d_in, const int* in_sizes, int n_in,
                              void* d_out, int out_size, void* d_ws, size_t ws_size,
                              hipStream_t stream) {
  const float* x      = (const float*)d_in[0];
  const float* ln1g   = (const float*)d_in[1];
  const float* ln1b   = (const float*)d_in[2];
  const float* w_qkv  = (const float*)d_in[3];
  const float* b_qkv  = (const float*)d_in[4];
  const float* w_proj = (const float*)d_in[5];
  const float* b_proj = (const float*)d_in[6];
  const float* ln2g   = (const float*)d_in[7];
  const float* ln2b   = (const float*)d_in[8];
  const float* w1     = (const float*)d_in[9];
  const float* b1     = (const float*)d_in[10];
  const float* w2     = (const float*)d_in[11];
  const float* b2     = (const float*)d_in[12];

  char* ws = (char*)d_ws;
  ushort* wqkvT  = (ushort*)(ws + 0);             // [6144][2048] bf16  24MB
  ushort* wprojT = (ushort*)(ws + 25165824);      // [2048][2048] bf16   8MB
  ushort* w1T    = (ushort*)(ws + 33554432);      // [8192][2048] bf16  32MB
  ushort* w2T    = (ushort*)(ws + 67108864);      // [2048][8192] bf16  32MB
  ushort* hbuf   = (ushort*)(ws + 100663296);     // [4096][2048] bf16  16MB (LN1/LN2 out)
  ushort* qpk    = (ushort*)(ws + 117440512);     // packed Q 16MB
  ushort* kpk    = (ushort*)(ws + 134217728);     // packed K 16MB
  ushort* vpk    = (ushort*)(ws + 150994944);     // packed V 16MB
  ushort* ctxb   = (ushort*)(ws + 167772160);     // [4096][2048] bf16  16MB
  ushort* gelu   = (ushort*)(ws + 117440512);     // [4096][8192] bf16  64MB (reuses q/k/v/ctx)
  float*  x2     = (float*)(ws + 184549376);      // [4096][2048] f32   32MB

  tcvt_kernel<<<dim3(96, 32),  256, 0, stream>>>(w_qkv,  wqkvT, 2048, 6144);
  tcvt_kernel<<<dim3(32, 32),  256, 0, stream>>>(w_proj, wprojT, 2048, 2048);
  tcvt_kernel<<<dim3(128, 32), 256, 0, stream>>>(w1,     w1T,   2048, 8192);
  tcvt_kernel<<<dim3(32, 128), 256, 0, stream>>>(w2,     w2T,   8192, 2048);

  // LN1 -> hbuf (bf16)
  ln_kernel<<<NTOK, 256, 0, stream>>>(x, ln1g, ln1b, hbuf);
  // QKV = h @ w_qkv + b_qkv, fragment-packed out. grid 24x32 = 768
  gemm3b_kernel<3><<<dim3(24, 32), 512, 0, stream>>>(
      hbuf, wqkvT, b_qkv, nullptr, nullptr, qpk, kpk, vpk, NTOK, QKVW, HID);
  // attention -> ctxb (bf16)
  attn_kernel<<<dim3(16, 2 * NHEAD), 256, 0, stream>>>(qpk, kpk, vpk, ctxb);
  // x2 = ctx @ w_proj + b_proj + x (f32). grid 8x32 = 256
  gemm3b_kernel<1><<<dim3(8, 32), 512, 0, stream>>>(
      ctxb, wprojT, b_proj, x, x2, nullptr, nullptr, nullptr, NTOK, HID, HID);
  // LN2 -> hbuf
  ln_kernel<<<NTOK, 256, 0, stream>>>(x2, ln2g, ln2b, hbuf);
  // g = gelu(h @ w1 + b1). grid 32x32 = 1024 (BM=128, 4 rounds/CU)
  gemm3b_kernel<2><<<dim3(32, 32), 512, 0, stream>>>(
      hbuf, w1T, b1, nullptr, gelu, nullptr, nullptr, nullptr, NTOK, NFFN, HID);
  // out = g @ w2 + b2 + x2. grid 8x32 = 256
  gemm3b_kernel<1><<<dim3(8, 32), 512, 0, stream>>>(
      gelu, w2T, b2, x2, (float*)d_out, nullptr, nullptr, nullptr, NTOK, HID, NFFN);
}

// Round 15
// 618.886 us; speedup vs baseline: 1.0823x; 1.0823x over previous
//
#include <hip/hip_runtime.h>
#include <hip/hip_bf16.h>
#include <math.h>

// ---------------------------------------------------------------------------
// BasicTransformer block on MI355X, bf16-MFMA implementation.
// B=2 S=2048 H=2048 NH=32 HD=64 FFN=8192
// R15: R13 config (best, 622us): FFN1 on gemm8p BM=256, QKV/proj/FFN2 on
// gemm3b 3-deep rotation. Plus: 4 tcvt launches merged into one kernel.
// ---------------------------------------------------------------------------

typedef __attribute__((ext_vector_type(8))) short bf16x8;
typedef __attribute__((ext_vector_type(4))) float f32x4;
typedef __attribute__((ext_vector_type(16))) float f32x16;

#define DEV __device__ __forceinline__

static constexpr int SEQ  = 2048;
static constexpr int HID  = 2048;
static constexpr int NHEAD = 32;
static constexpr int HDIM = 64;
static constexpr int NFFN = 8192;
static constexpr int NTOK = 2 * SEQ;       // 4096 rows
static constexpr int QKVW = 3 * HID;       // 6144

// 0.125 (1/sqrt(64)) * log2(e): folded into Q so P = exp2(S - m)
#define QSCALE 0.1803368801111204f

#if defined(__has_builtin)
#if __has_builtin(__builtin_amdgcn_exp2f)
#define EXP2(x) __builtin_amdgcn_exp2f(x)
#endif
#endif
#ifndef EXP2
#define EXP2(x) exp2f(x)
#endif

#define VMCNT(n) asm volatile("s_waitcnt vmcnt(" #n ")" ::: "memory")
#define SB0()    __builtin_amdgcn_sched_barrier(0)

DEV ushort f2bf(float f) {                 // RNE f32 -> bf16
  unsigned u = __float_as_uint(f);
  return (ushort)((u + 0x7fffu + ((u >> 16) & 1u)) >> 16);
}

DEV void gload16(const void* g, void* l) { // async global->LDS, 16B/lane
  __builtin_amdgcn_global_load_lds(
      (const __attribute__((address_space(1))) unsigned int*)g,
      (__attribute__((address_space(3))) unsigned int*)l, 16, 0, 0);
}

// ---------------------------------------------------------------------------
// merged transpose+convert: 4 weights in one launch. tile 64x64.
// in [R][C] f32 -> out [C][R] bf16.
// ---------------------------------------------------------------------------
DEV void tcvt_tile(const float* __restrict__ in, ushort* __restrict__ out,
                   int R, int C, int bx, int by) {
  __shared__ ushort tile[64][72];
  const int tr = by * 64, tc = bx * 64;
  const int t = threadIdx.x;
  const int rr = t >> 2, c4 = (t & 3) * 16;
  const float4* ip = (const float4*)(in + (size_t)(tr + rr) * C + tc + c4);
  float4 a0 = ip[0], a1 = ip[1], a2 = ip[2], a3 = ip[3];
  ushort* tp = &tile[rr][c4];
  tp[0]=f2bf(a0.x); tp[1]=f2bf(a0.y); tp[2]=f2bf(a0.z); tp[3]=f2bf(a0.w);
  tp[4]=f2bf(a1.x); tp[5]=f2bf(a1.y); tp[6]=f2bf(a1.z); tp[7]=f2bf(a1.w);
  tp[8]=f2bf(a2.x); tp[9]=f2bf(a2.y); tp[10]=f2bf(a2.z); tp[11]=f2bf(a2.w);
  tp[12]=f2bf(a3.x); tp[13]=f2bf(a3.y); tp[14]=f2bf(a3.z); tp[15]=f2bf(a3.w);
  __syncthreads();
  union { ushort u[8]; bf16x8 v; } p0, p1;
#pragma unroll
  for (int j = 0; j < 8; ++j) { p0.u[j] = tile[c4 + j][rr]; p1.u[j] = tile[c4 + 8 + j][rr]; }
  ushort* op = out + (size_t)(tc + rr) * R + tr + c4;
  *(bf16x8*)op = p0.v;
  *(bf16x8*)(op + 8) = p1.v;
}

__global__ __launch_bounds__(256) void tcvt_all_kernel(
    const float* __restrict__ wqkv, const float* __restrict__ wproj,
    const float* __restrict__ w1,   const float* __restrict__ w2,
    ushort* __restrict__ oqkv, ushort* __restrict__ oproj,
    ushort* __restrict__ o1,   ushort* __restrict__ o2) {
  int bid = blockIdx.x;
  if (bid < 3072) {                       // w_qkv [2048][6144], grid 96x32
    tcvt_tile(wqkv, oqkv, 2048, 6144, bid % 96, bid / 96);
  } else if (bid < 4096) {                // w_proj [2048][2048], grid 32x32
    bid -= 3072;
    tcvt_tile(wproj, oproj, 2048, 2048, bid % 32, bid / 32);
  } else if (bid < 8192) {                // w1 [2048][8192], grid 128x32
    bid -= 4096;
    tcvt_tile(w1, o1, 2048, 8192, bid % 128, bid / 128);
  } else {                                // w2 [8192][2048], grid 32x128
    bid -= 8192;
    tcvt_tile(w2, o2, 8192, 2048, bid % 32, bid / 32);
  }
}

// ---------------------------------------------------------------------------
// LayerNorm row kernel: x [rows][2048] f32 -> out bf16
// ---------------------------------------------------------------------------
__global__ __launch_bounds__(256) void ln_kernel(const float* __restrict__ x,
                                                 const float* __restrict__ g,
                                                 const float* __restrict__ bb,
                                                 ushort* __restrict__ out) {
  const int row = blockIdx.x, t = threadIdx.x;
  const float4* xv = (const float4*)(x + (size_t)row * HID);
  float4 a0 = xv[t * 2], a1 = xv[t * 2 + 1];
  float s  = a0.x + a0.y + a0.z + a0.w + a1.x + a1.y + a1.z + a1.w;
  float ss = a0.x*a0.x + a0.y*a0.y + a0.z*a0.z + a0.w*a0.w
           + a1.x*a1.x + a1.y*a1.y + a1.z*a1.z + a1.w*a1.w;
#pragma unroll
  for (int o = 32; o > 0; o >>= 1) { s += __shfl_down(s, o); ss += __shfl_down(ss, o); }
  __shared__ float red[8];
  const int w = t >> 6, l = t & 63;
  if (l == 0) { red[w] = s; red[4 + w] = ss; }
  __syncthreads();
  s  = red[0] + red[1] + red[2] + red[3];
  ss = red[4] + red[5] + red[6] + red[7];
  const float mu = s * (1.f / HID);
  const float rs = rsqrtf(ss * (1.f / HID) - mu * mu + 1e-5f);
  const float4* gv = (const float4*)g;
  const float4* bv = (const float4*)bb;
  float4 g0 = gv[t * 2], g1 = gv[t * 2 + 1], b0 = bv[t * 2], b1 = bv[t * 2 + 1];
  union { ushort u[8]; bf16x8 v; } p;
  p.u[0] = f2bf((a0.x - mu) * rs * g0.x + b0.x);
  p.u[1] = f2bf((a0.y - mu) * rs * g0.y + b0.y);
  p.u[2] = f2bf((a0.z - mu) * rs * g0.z + b0.z);
  p.u[3] = f2bf((a0.w - mu) * rs * g0.w + b0.w);
  p.u[4] = f2bf((a1.x - mu) * rs * g1.x + b1.x);
  p.u[5] = f2bf((a1.y - mu) * rs * g1.y + b1.y);
  p.u[6] = f2bf((a1.z - mu) * rs * g1.z + b1.z);
  p.u[7] = f2bf((a1.w - mu) * rs * g1.w + b1.w);
  *(bf16x8*)(out + (size_t)row * HID + t * 8) = p.v;
}

// ---------------------------------------------------------------------------
// QKV fragment-packed store (layout the attn kernel consumes).
// ---------------------------------------------------------------------------
DEV void qkv_store(int row, int col, float v,
                   ushort* __restrict__ qpk, ushort* __restrict__ kpk,
                   ushort* __restrict__ vpk) {
  const int h = col / 192;
  const int c = col - h * 192;
  const int bh2 = (row >> 11) * 32 + h;
  const int t32 = (row >> 5) & 63;
  const int r5 = row & 31;
  if (c < 64) {
    const int s = c >> 4, hi2 = (c >> 3) & 1, j = c & 7;
    qpk[(((size_t)bh2 * 64 + t32) * 4 + s) * 512 + (hi2 * 32 + r5) * 8 + j] = f2bf(v * QSCALE);
  } else if (c < 128) {
    const int d = c - 64;
    const int s = d >> 4, hi2 = (d >> 3) & 1, j = d & 7;
    kpk[(((size_t)bh2 * 64 + t32) * 4 + s) * 512 + (hi2 * 32 + r5) * 8 + j] = f2bf(v);
  } else {
    const int d = c - 128;
    const int ks = r5 >> 4, hi2 = (r5 >> 3) & 1, j = r5 & 7;
    const int half = d >> 5, dl = d & 31;
    vpk[((((size_t)bh2 * 64 + t32) * 2 + ks) * 2 + half) * 512 + (hi2 * 32 + dl) * 8 + j] = f2bf(v);
  }
}

// ---------------------------------------------------------------------------
// R6/R11 GEMM (verified): counted-vmcnt half-set pipeline. Used for FFN1.
// ---------------------------------------------------------------------------
template <int BM, int EPI>
__global__ __launch_bounds__(512, 2) void gemm8p_kernel(
    const ushort* __restrict__ A, const ushort* __restrict__ BT,
    const float* __restrict__ bias, const float* __restrict__ res,
    void* __restrict__ outv,
    ushort* __restrict__ qpk, ushort* __restrict__ kpk, ushort* __restrict__ vpk,
    int M, int N, int K) {
  constexpr int MR = BM / 32;
  constexpr int MH = BM / 64;

  __shared__ ushort lds[2 * (BM * 64 + 256 * 64)];
  char* const a0p = (char*)lds;
  char* const b0p = a0p + BM * 128;
  char* const a1p = b0p + 32768;
  char* const b1p = a1p + BM * 128;

  const int t = threadIdx.x;
  const int w = t >> 6, l = t & 63;
  const int l16 = l & 15, lg = l >> 4;
  const int lr = l >> 3, lsl = l & 7;
  const int wm = w >> 2, wn = w & 3;
  const int l7 = l & 7;

  const int nwg = gridDim.x * gridDim.y;
  const int lin = blockIdx.y * gridDim.x + blockIdx.x;
  const int work = (lin & 7) * (nwg >> 3) + (lin >> 3);
  const int bn = work % gridDim.x, bm = work / gridDim.x;
  const int tm = bm * BM, tn = bn * 256;

  const int xk0 = (lg ^ l7) << 4;
  const int xk1 = ((lg + 4) ^ l7) << 4;
  const int aoff = (wm * (BM / 2) + l16) * 128;
  const int boff = (wn * 64 + l16) * 128;
  const char* rA0k0 = a0p + aoff + xk0;  const char* rA0k1 = a0p + aoff + xk1;
  const char* rA1k0 = a1p + aoff + xk0;  const char* rA1k1 = a1p + aoff + xk1;
  const char* rB0k0 = b0p + boff + xk0;  const char* rB0k1 = b0p + boff + xk1;
  const char* rB1k0 = b1p + boff + xk0;  const char* rB1k1 = b1p + boff + xk1;

  int rA00, rA01, rA10, rA11;
  if (BM == 256) {
    rA00 = 0 * 128 + 0 * 64 + w * 8 + lr;  rA01 = 1 * 128 + 0 * 64 + w * 8 + lr;
    rA10 = 0 * 128 + 1 * 64 + w * 8 + lr;  rA11 = 1 * 128 + 1 * 64 + w * 8 + lr;
  } else {
    const int ri = w * 8 + lr;
    rA00 = (ri >> 5) * 64 + 0 * 32 + (ri & 31);
    rA10 = (ri >> 5) * 64 + 1 * 32 + (ri & 31);
    rA01 = rA00; rA11 = rA10;
  }
  const int riB0 = w * 8 + lr, riB1 = 64 + w * 8 + lr;
  const int rB00 = (riB0 >> 5) * 64 + (riB0 & 31);
  const int rB01 = (riB1 >> 5) * 64 + (riB1 & 31);
  const int rB10 = (riB0 >> 5) * 64 + 32 + (riB0 & 31);
  const int rB11 = (riB1 >> 5) * 64 + 32 + (riB1 & 31);
  const int gcol = (lsl ^ lr) << 3;
  const ushort* pa00 = A + (size_t)(tm + rA00) * K + gcol;
  const ushort* pa01 = A + (size_t)(tm + rA01) * K + gcol;
  const ushort* pa10 = A + (size_t)(tm + rA10) * K + gcol;
  const ushort* pa11 = A + (size_t)(tm + rA11) * K + gcol;
  const ushort* pb00 = BT + (size_t)(tn + rB00) * K + gcol;
  const ushort* pb01 = BT + (size_t)(tn + rB01) * K + gcol;
  const ushort* pb10 = BT + (size_t)(tn + rB10) * K + gcol;
  const ushort* pb11 = BT + (size_t)(tn + rB11) * K + gcol;
  const int da00 = rA00 * 128 + lsl * 16, da01 = rA01 * 128 + lsl * 16;
  const int da10 = rA10 * 128 + lsl * 16, da11 = rA11 * 128 + lsl * 16;
  const int db00 = rB00 * 128 + lsl * 16, db01 = rB01 * 128 + lsl * 16;
  const int db10 = rB10 * 128 + lsl * 16, db11 = rB11 * 128 + lsl * 16;

  const f32x4 z4 = {0.f, 0.f, 0.f, 0.f};
  f32x4 acc[MR][4];
#pragma unroll
  for (int i = 0; i < MR; ++i)
#pragma unroll
    for (int j = 0; j < 4; ++j) acc[i][j] = z4;

  auto ktile = [&](const char* rAk0, const char* rAk1,
                   const char* rBk0, const char* rBk1,
                   char* NA, char* NB, int ktn, bool dost) {
    bf16x8 af[MH][2], bfr[2][2];
#pragma unroll
    for (int q = 0; q < 4; ++q) {
      const int mh = q >> 1, nh = q & 1;
      if ((q & 1) == 0) {
#pragma unroll
        for (int mi = 0; mi < MH; ++mi) {
          af[mi][0] = *(const bf16x8*)(rAk0 + mh * (BM / 4) * 128 + mi * 2048);
          af[mi][1] = *(const bf16x8*)(rAk1 + mh * (BM / 4) * 128 + mi * 2048);
        }
      }
#pragma unroll
      for (int ni = 0; ni < 2; ++ni) {
        bfr[ni][0] = *(const bf16x8*)(rBk0 + nh * 4096 + ni * 2048);
        bfr[ni][1] = *(const bf16x8*)(rBk1 + nh * 4096 + ni * 2048);
      }
      if (dost && q < 2) {
        if (q == 0) {
          gload16(pa00 + ktn, NA + da00);
          if (BM == 256) gload16(pa01 + ktn, NA + da01);
          gload16(pb00 + ktn, NB + db00);
          gload16(pb01 + ktn, NB + db01);
        } else {
          gload16(pa10 + ktn, NA + da10);
          if (BM == 256) gload16(pa11 + ktn, NA + da11);
          gload16(pb10 + ktn, NB + db10);
          gload16(pb11 + ktn, NB + db11);
        }
      }
      if (q == 0) {
        if (dost) { if (BM == 256) VMCNT(4); else VMCNT(3); }
        else VMCNT(0);
      }
      if (q == 3 && dost) { if (BM == 256) VMCNT(4); else VMCNT(3); }
      __builtin_amdgcn_s_barrier();
      asm volatile("s_waitcnt lgkmcnt(0)" ::: "memory");
      SB0();
      __builtin_amdgcn_s_setprio(1);
#pragma unroll
      for (int mi = 0; mi < MH; ++mi)
#pragma unroll
        for (int ni = 0; ni < 2; ++ni)
#pragma unroll
          for (int ks = 0; ks < 2; ++ks)
            acc[mh * MH + mi][nh * 2 + ni] = __builtin_amdgcn_mfma_f32_16x16x32_bf16(
                af[mi][ks], bfr[ni][ks], acc[mh * MH + mi][nh * 2 + ni], 0, 0, 0);
      __builtin_amdgcn_s_setprio(0);
    }
  };

  gload16(pa00, a0p + da00);
  if (BM == 256) gload16(pa01, a0p + da01);
  gload16(pb00, b0p + db00);
  gload16(pb01, b0p + db01);
  gload16(pa10, a0p + da10);
  if (BM == 256) gload16(pa11, a0p + da11);
  gload16(pb10, b0p + db10);
  gload16(pb11, b0p + db11);
  VMCNT(0);
  __builtin_amdgcn_s_barrier();

  const int nt = K >> 6;
  for (int it = 0; it < nt; it += 2) {
    ktile(rA0k0, rA0k1, rB0k0, rB0k1, a1p, b1p, (it + 1) << 6, true);
    ktile(rA1k0, rA1k1, rB1k0, rB1k1, a0p, b0p, (it + 2) << 6, (it + 2) < nt);
  }

  const int row0 = tm + wm * (BM / 2) + lg * 4;
  const int col0 = tn + wn * 64 + l16;
#pragma unroll
  for (int ni = 0; ni < 4; ++ni) {
    const int col = col0 + ni * 16;
    const float bvl = bias[col];
#pragma unroll
    for (int mi = 0; mi < MR; ++mi) {
#pragma unroll
      for (int r = 0; r < 4; ++r) {
        const int row = row0 + mi * 16 + r;
        float v = acc[mi][ni][r] + bvl;
        if (EPI == 1) {
          const size_t off = (size_t)row * N + col;
          ((float*)outv)[off] = v + res[off];
        } else if (EPI == 2) {
          const float u = 0.7978845608f * (v + 0.044715f * v * v * v);
          ((ushort*)outv)[(size_t)row * N + col] = f2bf(v / (1.f + __expf(-2.f * u)));
        } else if (EPI == 3) {
          qkv_store(row, col, v, qpk, kpk, vpk);
        } else {
          ((ushort*)outv)[(size_t)row * N + col] = f2bf(v);
        }
      }
    }
  }
}

// ---------------------------------------------------------------------------
// R13 3-deep buffer rotation GEMM, BM=128, BN=256, BK=64, 512 thr.
// Whole-tile stage at tile top; one lgkm(0)+vmcnt(6)+barrier per K-tile.
// ---------------------------------------------------------------------------
#define G3BODY(CB, SB)                                                         \
  {                                                                            \
    const bool s2_ = (tt + 2) < nt;                                            \
    if (s2_) {                                                                 \
      const int k2_ = (tt + 2) << 6;                                           \
      gload16(ga0 + k2_, Ab##SB + da0); gload16(ga1 + k2_, Ab##SB + da1);      \
      gload16(gb0 + k2_, Bb##SB + db0); gload16(gb1 + k2_, Bb##SB + db1);      \
      gload16(gb2 + k2_, Bb##SB + db2); gload16(gb3 + k2_, Bb##SB + db3);      \
    }                                                                          \
    bf16x8 af_[4][2], bf_[4][2];                                               \
    _Pragma("unroll") for (int mf = 0; mf < 4; ++mf) {                         \
      af_[mf][0] = *(const bf16x8*)(pA##CB##0 + mf * 2048);                    \
      af_[mf][1] = *(const bf16x8*)(pA##CB##1 + mf * 2048);                    \
    }                                                                          \
    _Pragma("unroll") for (int nf = 0; nf < 4; ++nf) {                         \
      bf_[nf][0] = *(const bf16x8*)(pB##CB##0 + nf * 2048);                    \
      bf_[nf][1] = *(const bf16x8*)(pB##CB##1 + nf * 2048);                    \
    }                                                                          \
    __builtin_amdgcn_s_setprio(1);                                             \
    _Pragma("unroll") for (int mf = 0; mf < 4; ++mf)                           \
      _Pragma("unroll") for (int nf = 0; nf < 4; ++nf)                         \
        _Pragma("unroll") for (int ks = 0; ks < 2; ++ks)                       \
          acc[mf][nf] = __builtin_amdgcn_mfma_f32_16x16x32_bf16(               \
              af_[mf][ks], bf_[nf][ks], acc[mf][nf], 0, 0, 0);                 \
    __builtin_amdgcn_s_setprio(0);                                             \
    asm volatile("s_waitcnt lgkmcnt(0)" ::: "memory");                         \
    if (s2_) { VMCNT(6); }                                                     \
    else if (tt + 1 < nt) { VMCNT(0); }                                        \
    __builtin_amdgcn_s_barrier();                                              \
  }

template <int EPI>
__global__ __launch_bounds__(512, 2) void gemm3b_kernel(
    const ushort* __restrict__ A, const ushort* __restrict__ BT,
    const float* __restrict__ bias, const float* __restrict__ res,
    void* __restrict__ outv,
    ushort* __restrict__ qpk, ushort* __restrict__ kpk, ushort* __restrict__ vpk,
    int M, int N, int K) {
  __shared__ ushort lds[73728];              // 144 KiB = 3 x (16KB A + 32KB B)
  char* const L = (char*)lds;
  char* const Ab0 = L;             char* const Bb0 = L + 16384;
  char* const Ab1 = L + 49152;     char* const Bb1 = Ab1 + 16384;
  char* const Ab2 = L + 98304;     char* const Bb2 = Ab2 + 16384;

  const int t = threadIdx.x;
  const int w = t >> 6, l = t & 63;
  const int l16 = l & 15, lg = l >> 4, lr = l >> 3, lsl = l & 7, l7 = l & 7;
  const int wm = w >> 2, wn = w & 3;

  const int nwg = gridDim.x * gridDim.y;
  const int lin = blockIdx.y * gridDim.x + blockIdx.x;
  const int work = (lin & 7) * (nwg >> 3) + (lin >> 3);
  const int bn = work % gridDim.x, bm = work / gridDim.x;
  const int tm = bm * 128, tn = bn * 256;

  const int xk0 = (lg ^ l7) << 4, xk1 = ((4 + lg) ^ l7) << 4;
  const int aoff = (wm * 64 + l16) * 128;
  const int boff = (wn * 64 + l16) * 128;
  const char* pA00 = Ab0 + aoff + xk0;  const char* pA01 = Ab0 + aoff + xk1;
  const char* pA10 = Ab1 + aoff + xk0;  const char* pA11 = Ab1 + aoff + xk1;
  const char* pA20 = Ab2 + aoff + xk0;  const char* pA21 = Ab2 + aoff + xk1;
  const char* pB00 = Bb0 + boff + xk0;  const char* pB01 = Bb0 + boff + xk1;
  const char* pB10 = Bb1 + boff + xk0;  const char* pB11 = Bb1 + boff + xk1;
  const char* pB20 = Bb2 + boff + xk0;  const char* pB21 = Bb2 + boff + xk1;

  const int ri = w * 8 + lr;
  const int rA0 = (ri >> 5) * 64 + (ri & 31);
  const int rA1 = rA0 + 32;
  const int ri2 = 64 + ri;
  const int rB0 = rA0;
  const int rB1 = (ri2 >> 5) * 64 + (ri2 & 31);
  const int rB2 = rB0 + 32;
  const int rB3 = rB1 + 32;
  const int gcol = (lsl ^ lr) << 3;
  const ushort* ga0 = A + (size_t)(tm + rA0) * K + gcol;
  const ushort* ga1 = A + (size_t)(tm + rA1) * K + gcol;
  const ushort* gb0 = BT + (size_t)(tn + rB0) * K + gcol;
  const ushort* gb1 = BT + (size_t)(tn + rB1) * K + gcol;
  const ushort* gb2 = BT + (size_t)(tn + rB2) * K + gcol;
  const ushort* gb3 = BT + (size_t)(tn + rB3) * K + gcol;
  const int da0 = rA0 * 128 + lsl * 16, da1 = rA1 * 128 + lsl * 16;
  const int db0 = rB0 * 128 + lsl * 16, db1 = rB1 * 128 + lsl * 16;
  const int db2 = rB2 * 128 + lsl * 16, db3 = rB3 * 128 + lsl * 16;

  const f32x4 z4 = {0.f, 0.f, 0.f, 0.f};
  f32x4 acc[4][4];
#pragma unroll
  for (int i = 0; i < 4; ++i)
#pragma unroll
    for (int j = 0; j < 4; ++j) acc[i][j] = z4;

  const int nt = K >> 6;

  gload16(ga0, Ab0 + da0); gload16(ga1, Ab0 + da1);
  gload16(gb0, Bb0 + db0); gload16(gb1, Bb0 + db1);
  gload16(gb2, Bb0 + db2); gload16(gb3, Bb0 + db3);
  gload16(ga0 + 64, Ab1 + da0); gload16(ga1 + 64, Ab1 + da1);
  gload16(gb0 + 64, Bb1 + db0); gload16(gb1 + 64, Bb1 + db1);
  gload16(gb2 + 64, Bb1 + db2); gload16(gb3 + 64, Bb1 + db3);
  VMCNT(6);
  __builtin_amdgcn_s_barrier();

  int tt = 0;
  while (true) {
    G3BODY(0, 2); ++tt; if (tt >= nt) break;
    G3BODY(1, 0); ++tt; if (tt >= nt) break;
    G3BODY(2, 1); ++tt; if (tt >= nt) break;
  }

  const int row0 = tm + wm * 64 + lg * 4;
  const int col0 = tn + wn * 64 + l16;
#pragma unroll
  for (int ni = 0; ni < 4; ++ni) {
    const int col = col0 + ni * 16;
    const float bvl = bias[col];
#pragma unroll
    for (int mi = 0; mi < 4; ++mi) {
#pragma unroll
      for (int r = 0; r < 4; ++r) {
        const int row = row0 + mi * 16 + r;
        float v = acc[mi][ni][r] + bvl;
        if (EPI == 1) {
          const size_t off = (size_t)row * N + col;
          ((float*)outv)[off] = v + res[off];
        } else if (EPI == 2) {
          const float u = 0.7978845608f * (v + 0.044715f * v * v * v);
          ((ushort*)outv)[(size_t)row * N + col] = f2bf(v / (1.f + __expf(-2.f * u)));
        } else if (EPI == 3) {
          qkv_store(row, col, v, qpk, kpk, vpk);
        } else {
          ((ushort*)outv)[(size_t)row * N + col] = f2bf(v);
        }
      }
    }
  }
}

// ---------------------------------------------------------------------------
// Flash attention: zero-LDS, all operands fragment-packed & coalesced.
// Grid (16,64). 4 indep waves/block, wave = 32 q rows, KV tile = 32.
// ---------------------------------------------------------------------------
__global__ __launch_bounds__(256) void attn_kernel(const ushort* __restrict__ qpk,
                                                   const ushort* __restrict__ kpk,
                                                   const ushort* __restrict__ vpk,
                                                   ushort* __restrict__ ctx) {
  const int lin = blockIdx.x + blockIdx.y * gridDim.x;
  const int work = (lin & 7) * 128 + (lin >> 3);
  const int qt = work & 15, bh = work >> 4;
  const int b = bh >> 5, h = bh & 31;
  const int t = threadIdx.x, w = t >> 6, l = t & 63;
  const int l32 = l & 31, hi = l >> 5;

  const ushort* qb = qpk + ((((size_t)bh * 64 + qt * 4 + w) * 4) * 64 + l) * 8;
  bf16x8 qf0 = *(const bf16x8*)(qb);
  bf16x8 qf1 = *(const bf16x8*)(qb + 512);
  bf16x8 qf2 = *(const bf16x8*)(qb + 1024);
  bf16x8 qf3 = *(const bf16x8*)(qb + 1536);

  const ushort* kbase = kpk + (size_t)bh * 131072 + l * 8;
  const ushort* vbase = vpk + (size_t)bh * 131072 + l * 8;

  f32x16 oacc0, oacc1;
#pragma unroll
  for (int r = 0; r < 16; ++r) { oacc0[r] = 0.f; oacc1[r] = 0.f; }
  float m = -1e30f, lsum = 0.f;
  const f32x16 z16 = {};

#define LOADK(k0, k1, k2, k3, kt) {                                           \
    const ushort* p_ = kbase + (size_t)(kt) * 2048;                           \
    k0 = *(const bf16x8*)(p_);        k1 = *(const bf16x8*)(p_ + 512);        \
    k2 = *(const bf16x8*)(p_ + 1024); k3 = *(const bf16x8*)(p_ + 1536); }
#define LOADV(v0, v1, v2, v3, kt) {                                           \
    const ushort* p_ = vbase + (size_t)(kt) * 2048;                           \
    v0 = *(const bf16x8*)(p_);        v1 = *(const bf16x8*)(p_ + 512);        \
    v2 = *(const bf16x8*)(p_ + 1024); v3 = *(const bf16x8*)(p_ + 1536); }

#define STEP(k0, k1, k2, k3, v0, v1, v2, v3) {                                \
    f32x16 s = __builtin_amdgcn_mfma_f32_32x32x16_bf16(k0, qf0, z16, 0, 0, 0);\
    s = __builtin_amdgcn_mfma_f32_32x32x16_bf16(k1, qf1, s, 0, 0, 0);         \
    s = __builtin_amdgcn_mfma_f32_32x32x16_bf16(k2, qf2, s, 0, 0, 0);         \
    s = __builtin_amdgcn_mfma_f32_32x32x16_bf16(k3, qf3, s, 0, 0, 0);         \
    float tm_ = s[0];                                                         \
    _Pragma("unroll") for (int r = 1; r < 16; ++r) tm_ = fmaxf(tm_, s[r]);    \
    tm_ = fmaxf(tm_, __shfl_xor(tm_, 32));                                    \
    if (!__all(tm_ - m <= 8.f)) {                                             \
      const float mn = fmaxf(m, tm_);                                         \
      const float sf = EXP2(m - mn);                                          \
      m = mn;                                                                 \
      lsum *= sf;                                                             \
      _Pragma("unroll") for (int r = 0; r < 16; ++r) {                        \
        const float f = __shfl(sf, (r & 3) + 8 * (r >> 2) + 4 * hi);          \
        oacc0[r] *= f; oacc1[r] *= f;                                         \
      }                                                                       \
    }                                                                         \
    float p[16];                                                              \
    _Pragma("unroll") for (int r = 0; r < 16; ++r) p[r] = EXP2(s[r] - m);     \
    float ls = 0.f;                                                           \
    _Pragma("unroll") for (int r = 0; r < 16; ++r) ls += p[r];                \
    lsum += ls;                                                               \
    unsigned pw[8];                                                           \
    _Pragma("unroll") for (int i = 0; i < 8; ++i)                             \
      asm("v_cvt_pk_bf16_f32 %0, %1, %2" : "=v"(pw[i]) : "v"(p[2*i]), "v"(p[2*i+1])); \
    unsigned a0 = pw[0], b0 = pw[2];                                          \
    asm("v_permlane32_swap_b32 %0, %1" : "+v"(a0), "+v"(b0));                 \
    unsigned a1 = pw[1], b1 = pw[3];                                          \
    asm("v_permlane32_swap_b32 %0, %1" : "+v"(a1), "+v"(b1));                 \
    unsigned a2 = pw[4], b2 = pw[6];                                          \
    asm("v_permlane32_swap_b32 %0, %1" : "+v"(a2), "+v"(b2));                 \
    unsigned a3 = pw[5], b3 = pw[7];                                          \
    asm("v_permlane32_swap_b32 %0, %1" : "+v"(a3), "+v"(b3));                 \
    union { unsigned uw[4]; bf16x8 v; } pa0, pa1;                             \
    pa0.uw[0] = a0; pa0.uw[1] = a1; pa0.uw[2] = b0; pa0.uw[3] = b1;           \
    pa1.uw[0] = a2; pa1.uw[1] = a3; pa1.uw[2] = b2; pa1.uw[3] = b3;           \
    oacc0 = __builtin_amdgcn_mfma_f32_32x32x16_bf16(pa0.v, v0, oacc0, 0, 0, 0);\
    oacc1 = __builtin_amdgcn_mfma_f32_32x32x16_bf16(pa0.v, v1, oacc1, 0, 0, 0);\
    oacc0 = __builtin_amdgcn_mfma_f32_32x32x16_bf16(pa1.v, v2, oacc0, 0, 0, 0);\
    oacc1 = __builtin_amdgcn_mfma_f32_32x32x16_bf16(pa1.v, v3, oacc1, 0, 0, 0);}

  bf16x8 ka0, ka1, ka2, ka3, kc0, kc1, kc2, kc3;
  LOADK(ka0, ka1, ka2, ka3, 0);
  for (int kt = 0; kt < 64; kt += 2) {
    bf16x8 va0, va1, va2, va3;
    LOADV(va0, va1, va2, va3, kt);
    LOADK(kc0, kc1, kc2, kc3, kt + 1);
    STEP(ka0, ka1, ka2, ka3, va0, va1, va2, va3);
    LOADV(va0, va1, va2, va3, kt + 1);
    if (kt + 2 < 64) LOADK(ka0, ka1, ka2, ka3, kt + 2);
    STEP(kc0, kc1, kc2, kc3, va0, va1, va2, va3);
  }
#undef LOADK
#undef LOADV
#undef STEP

  const float lf = lsum + __shfl_xor(lsum, 32);
  const float linv = 1.f / lf;
#pragma unroll
  for (int r = 0; r < 16; ++r) {
    const int qr = (r & 3) + 8 * (r >> 2);
    const float fac = __shfl(linv, qr + 4 * hi);
    const int row = qt * 128 + w * 32 + qr + 4 * hi;
    const size_t base = ((size_t)(b * SEQ + row)) * HID + h * 64 + l32;
    ctx[base]      = f2bf(oacc0[r] * fac);
    ctx[base + 32] = f2bf(oacc1[r] * fac);
  }
}

// ---------------------------------------------------------------------------
extern "C" void kernel_launch(void* const* d_in, const int* in_sizes, int n_in,
                              void* d_out, int out_size, void* d_ws, size_t ws_size,
                              hipStream_t stream) {
  const float* x      = (const float*)d_in[0];
  const float* ln1g   = (const float*)d_in[1];
  const float* ln1b   = (const float*)d_in[2];
  const float* w_qkv  = (const float*)d_in[3];
  const float* b_qkv  = (const float*)d_in[4];
  const float* w_proj = (const float*)d_in[5];
  const float* b_proj = (const float*)d_in[6];
  const float* ln2g   = (const float*)d_in[7];
  const float* ln2b   = (const float*)d_in[8];
  const float* w1     = (const float*)d_in[9];
  const float* b1     = (const float*)d_in[10];
  const float* w2     = (const float*)d_in[11];
  const float* b2     = (const float*)d_in[12];

  char* ws = (char*)d_ws;
  ushort* wqkvT  = (ushort*)(ws + 0);             // [6144][2048] bf16  24MB
  ushort* wprojT = (ushort*)(ws + 25165824);      // [2048][2048] bf16   8MB
  ushort* w1T    = (ushort*)(ws + 33554432);      // [8192][2048] bf16  32MB
  ushort* w2T    = (ushort*)(ws + 67108864);      // [2048][8192] bf16  32MB
  ushort* hbuf   = (ushort*)(ws + 100663296);     // [4096][2048] bf16  16MB (LN1/LN2 out)
  ushort* qpk    = (ushort*)(ws + 117440512);     // packed Q 16MB
  ushort* kpk    = (ushort*)(ws + 134217728);     // packed K 16MB
  ushort* vpk    = (ushort*)(ws + 150994944);     // packed V 16MB
  ushort* ctxb   = (ushort*)(ws + 167772160);     // [4096][2048] bf16  16MB
  ushort* gelu   = (ushort*)(ws + 117440512);     // [4096][8192] bf16  64MB (reuses q/k/v/ctx)
  float*  x2     = (float*)(ws + 184549376);      // [4096][2048] f32   32MB

  // all four weight transposes in ONE launch (12288 blocks)
  tcvt_all_kernel<<<12288, 256, 0, stream>>>(w_qkv, w_proj, w1, w2,
                                             wqkvT, wprojT, w1T, w2T);

  // LN1 -> hbuf (bf16)
  ln_kernel<<<NTOK, 256, 0, stream>>>(x, ln1g, ln1b, hbuf);
  // QKV = h @ w_qkv + b_qkv, fragment-packed out. grid 24x32 = 768
  gemm3b_kernel<3><<<dim3(24, 32), 512, 0, stream>>>(
      hbuf, wqkvT, b_qkv, nullptr, nullptr, qpk, kpk, vpk, NTOK, QKVW, HID);
  // attention -> ctxb (bf16)
  attn_kernel<<<dim3(16, 2 * NHEAD), 256, 0, stream>>>(qpk, kpk, vpk, ctxb);
  // x2 = ctx @ w_proj + b_proj + x (f32). grid 8x32 = 256
  gemm3b_kernel<1><<<dim3(8, 32), 512, 0, stream>>>(
      ctxb, wprojT, b_proj, x, x2, nullptr, nullptr, nullptr, NTOK, HID, HID);
  // LN2 -> hbuf
  ln_kernel<<<NTOK, 256, 0, stream>>>(x2, ln2g, ln2b, hbuf);
  // g = gelu(h @ w1 + b1). gemm8p BM=256, grid 32x16 = 512 (verified best)
  gemm8p_kernel<256, 2><<<dim3(32, 16), 512, 0, stream>>>(
      hbuf, w1T, b1, nullptr, gelu, nullptr, nullptr, nullptr, NTOK, NFFN, HID);
  // out = g @ w2 + b2 + x2. grid 8x32 = 256
  gemm3b_kernel<1><<<dim3(8, 32), 512, 0, stream>>>(
      gelu, w2T, b2, x2, (float*)d_out, nullptr, nullptr, nullptr, NTOK, HID, NFFN);
}

// Round 16
// 610.497 us; speedup vs baseline: 1.0971x; 1.0137x over previous
//
#include <hip/hip_runtime.h>
#include <hip/hip_bf16.h>
#include <math.h>

// ---------------------------------------------------------------------------
// BasicTransformer block on MI355X, bf16-MFMA implementation.
// B=2 S=2048 H=2048 NH=32 HD=64 FFN=8192
// R16: R15 (best, 619us) + mid-residual x2 stored bf16 (saves ~48MB serial
// HBM traffic across proj-write / LN2-read / FFN2-residual-read).
// ---------------------------------------------------------------------------

typedef __attribute__((ext_vector_type(8))) short bf16x8;
typedef __attribute__((ext_vector_type(4))) float f32x4;
typedef __attribute__((ext_vector_type(16))) float f32x16;

#define DEV __device__ __forceinline__

static constexpr int SEQ  = 2048;
static constexpr int HID  = 2048;
static constexpr int NHEAD = 32;
static constexpr int HDIM = 64;
static constexpr int NFFN = 8192;
static constexpr int NTOK = 2 * SEQ;       // 4096 rows
static constexpr int QKVW = 3 * HID;       // 6144

// 0.125 (1/sqrt(64)) * log2(e): folded into Q so P = exp2(S - m)
#define QSCALE 0.1803368801111204f

#if defined(__has_builtin)
#if __has_builtin(__builtin_amdgcn_exp2f)
#define EXP2(x) __builtin_amdgcn_exp2f(x)
#endif
#endif
#ifndef EXP2
#define EXP2(x) exp2f(x)
#endif

#define VMCNT(n) asm volatile("s_waitcnt vmcnt(" #n ")" ::: "memory")
#define SB0()    __builtin_amdgcn_sched_barrier(0)

DEV ushort f2bf(float f) {                 // RNE f32 -> bf16
  unsigned u = __float_as_uint(f);
  return (ushort)((u + 0x7fffu + ((u >> 16) & 1u)) >> 16);
}

DEV float bf2f(ushort u) { return __uint_as_float((unsigned)u << 16); }

DEV void gload16(const void* g, void* l) { // async global->LDS, 16B/lane
  __builtin_amdgcn_global_load_lds(
      (const __attribute__((address_space(1))) unsigned int*)g,
      (__attribute__((address_space(3))) unsigned int*)l, 16, 0, 0);
}

// ---------------------------------------------------------------------------
// merged transpose+convert: 4 weights in one launch. tile 64x64.
// ---------------------------------------------------------------------------
DEV void tcvt_tile(const float* __restrict__ in, ushort* __restrict__ out,
                   int R, int C, int bx, int by) {
  __shared__ ushort tile[64][72];
  const int tr = by * 64, tc = bx * 64;
  const int t = threadIdx.x;
  const int rr = t >> 2, c4 = (t & 3) * 16;
  const float4* ip = (const float4*)(in + (size_t)(tr + rr) * C + tc + c4);
  float4 a0 = ip[0], a1 = ip[1], a2 = ip[2], a3 = ip[3];
  ushort* tp = &tile[rr][c4];
  tp[0]=f2bf(a0.x); tp[1]=f2bf(a0.y); tp[2]=f2bf(a0.z); tp[3]=f2bf(a0.w);
  tp[4]=f2bf(a1.x); tp[5]=f2bf(a1.y); tp[6]=f2bf(a1.z); tp[7]=f2bf(a1.w);
  tp[8]=f2bf(a2.x); tp[9]=f2bf(a2.y); tp[10]=f2bf(a2.z); tp[11]=f2bf(a2.w);
  tp[12]=f2bf(a3.x); tp[13]=f2bf(a3.y); tp[14]=f2bf(a3.z); tp[15]=f2bf(a3.w);
  __syncthreads();
  union { ushort u[8]; bf16x8 v; } p0, p1;
#pragma unroll
  for (int j = 0; j < 8; ++j) { p0.u[j] = tile[c4 + j][rr]; p1.u[j] = tile[c4 + 8 + j][rr]; }
  ushort* op = out + (size_t)(tc + rr) * R + tr + c4;
  *(bf16x8*)op = p0.v;
  *(bf16x8*)(op + 8) = p1.v;
}

__global__ __launch_bounds__(256) void tcvt_all_kernel(
    const float* __restrict__ wqkv, const float* __restrict__ wproj,
    const float* __restrict__ w1,   const float* __restrict__ w2,
    ushort* __restrict__ oqkv, ushort* __restrict__ oproj,
    ushort* __restrict__ o1,   ushort* __restrict__ o2) {
  int bid = blockIdx.x;
  if (bid < 3072) {
    tcvt_tile(wqkv, oqkv, 2048, 6144, bid % 96, bid / 96);
  } else if (bid < 4096) {
    bid -= 3072;
    tcvt_tile(wproj, oproj, 2048, 2048, bid % 32, bid / 32);
  } else if (bid < 8192) {
    bid -= 4096;
    tcvt_tile(w1, o1, 2048, 8192, bid % 128, bid / 128);
  } else {
    bid -= 8192;
    tcvt_tile(w2, o2, 8192, 2048, bid % 32, bid / 32);
  }
}

// ---------------------------------------------------------------------------
// LayerNorm: x [rows][2048] f32 -> out bf16
// ---------------------------------------------------------------------------
__global__ __launch_bounds__(256) void ln_kernel(const float* __restrict__ x,
                                                 const float* __restrict__ g,
                                                 const float* __restrict__ bb,
                                                 ushort* __restrict__ out) {
  const int row = blockIdx.x, t = threadIdx.x;
  const float4* xv = (const float4*)(x + (size_t)row * HID);
  float4 a0 = xv[t * 2], a1 = xv[t * 2 + 1];
  float s  = a0.x + a0.y + a0.z + a0.w + a1.x + a1.y + a1.z + a1.w;
  float ss = a0.x*a0.x + a0.y*a0.y + a0.z*a0.z + a0.w*a0.w
           + a1.x*a1.x + a1.y*a1.y + a1.z*a1.z + a1.w*a1.w;
#pragma unroll
  for (int o = 32; o > 0; o >>= 1) { s += __shfl_down(s, o); ss += __shfl_down(ss, o); }
  __shared__ float red[8];
  const int w = t >> 6, l = t & 63;
  if (l == 0) { red[w] = s; red[4 + w] = ss; }
  __syncthreads();
  s  = red[0] + red[1] + red[2] + red[3];
  ss = red[4] + red[5] + red[6] + red[7];
  const float mu = s * (1.f / HID);
  const float rs = rsqrtf(ss * (1.f / HID) - mu * mu + 1e-5f);
  const float4* gv = (const float4*)g;
  const float4* bv = (const float4*)bb;
  float4 g0 = gv[t * 2], g1 = gv[t * 2 + 1], b0 = bv[t * 2], b1 = bv[t * 2 + 1];
  union { ushort u[8]; bf16x8 v; } p;
  p.u[0] = f2bf((a0.x - mu) * rs * g0.x + b0.x);
  p.u[1] = f2bf((a0.y - mu) * rs * g0.y + b0.y);
  p.u[2] = f2bf((a0.z - mu) * rs * g0.z + b0.z);
  p.u[3] = f2bf((a0.w - mu) * rs * g0.w + b0.w);
  p.u[4] = f2bf((a1.x - mu) * rs * g1.x + b1.x);
  p.u[5] = f2bf((a1.y - mu) * rs * g1.y + b1.y);
  p.u[6] = f2bf((a1.z - mu) * rs * g1.z + b1.z);
  p.u[7] = f2bf((a1.w - mu) * rs * g1.w + b1.w);
  *(bf16x8*)(out + (size_t)row * HID + t * 8) = p.v;
}

// LayerNorm over bf16 input rows (for x2 stored as bf16).
__global__ __launch_bounds__(256) void ln_bf_kernel(const ushort* __restrict__ x,
                                                    const float* __restrict__ g,
                                                    const float* __restrict__ bb,
                                                    ushort* __restrict__ out) {
  const int row = blockIdx.x, t = threadIdx.x;
  union { ushort u[8]; bf16x8 v; } xin;
  xin.v = *(const bf16x8*)(x + (size_t)row * HID + t * 8);
  float f[8];
#pragma unroll
  for (int j = 0; j < 8; ++j) f[j] = bf2f(xin.u[j]);
  float s = 0.f, ss = 0.f;
#pragma unroll
  for (int j = 0; j < 8; ++j) { s += f[j]; ss += f[j] * f[j]; }
#pragma unroll
  for (int o = 32; o > 0; o >>= 1) { s += __shfl_down(s, o); ss += __shfl_down(ss, o); }
  __shared__ float red[8];
  const int w = t >> 6, l = t & 63;
  if (l == 0) { red[w] = s; red[4 + w] = ss; }
  __syncthreads();
  s  = red[0] + red[1] + red[2] + red[3];
  ss = red[4] + red[5] + red[6] + red[7];
  const float mu = s * (1.f / HID);
  const float rs = rsqrtf(ss * (1.f / HID) - mu * mu + 1e-5f);
  const float4* gv = (const float4*)g;
  const float4* bv = (const float4*)bb;
  float4 g0 = gv[t * 2], g1 = gv[t * 2 + 1], b0 = bv[t * 2], b1 = bv[t * 2 + 1];
  union { ushort u[8]; bf16x8 v; } p;
  p.u[0] = f2bf((f[0] - mu) * rs * g0.x + b0.x);
  p.u[1] = f2bf((f[1] - mu) * rs * g0.y + b0.y);
  p.u[2] = f2bf((f[2] - mu) * rs * g0.z + b0.z);
  p.u[3] = f2bf((f[3] - mu) * rs * g0.w + b0.w);
  p.u[4] = f2bf((f[4] - mu) * rs * g1.x + b1.x);
  p.u[5] = f2bf((f[5] - mu) * rs * g1.y + b1.y);
  p.u[6] = f2bf((f[6] - mu) * rs * g1.z + b1.z);
  p.u[7] = f2bf((f[7] - mu) * rs * g1.w + b1.w);
  *(bf16x8*)(out + (size_t)row * HID + t * 8) = p.v;
}

// ---------------------------------------------------------------------------
// QKV fragment-packed store (layout the attn kernel consumes).
// ---------------------------------------------------------------------------
DEV void qkv_store(int row, int col, float v,
                   ushort* __restrict__ qpk, ushort* __restrict__ kpk,
                   ushort* __restrict__ vpk) {
  const int h = col / 192;
  const int c = col - h * 192;
  const int bh2 = (row >> 11) * 32 + h;
  const int t32 = (row >> 5) & 63;
  const int r5 = row & 31;
  if (c < 64) {
    const int s = c >> 4, hi2 = (c >> 3) & 1, j = c & 7;
    qpk[(((size_t)bh2 * 64 + t32) * 4 + s) * 512 + (hi2 * 32 + r5) * 8 + j] = f2bf(v * QSCALE);
  } else if (c < 128) {
    const int d = c - 64;
    const int s = d >> 4, hi2 = (d >> 3) & 1, j = d & 7;
    kpk[(((size_t)bh2 * 64 + t32) * 4 + s) * 512 + (hi2 * 32 + r5) * 8 + j] = f2bf(v);
  } else {
    const int d = c - 128;
    const int ks = r5 >> 4, hi2 = (r5 >> 3) & 1, j = r5 & 7;
    const int half = d >> 5, dl = d & 31;
    vpk[((((size_t)bh2 * 64 + t32) * 2 + ks) * 2 + half) * 512 + (hi2 * 32 + dl) * 8 + j] = f2bf(v);
  }
}

// Shared epilogue-op. EPI: 1 +bias+f32res->f32   2 +bias,gelu->bf16
// 3 QKV-pack   4 +bias+f32res->bf16   5 +bias+bf16res->f32
template <int EPI>
DEV void epi_store(void* __restrict__ outv, const float* __restrict__ res,
                   ushort* __restrict__ qpk, ushort* __restrict__ kpk,
                   ushort* __restrict__ vpk, int row, int col, int N, float v) {
  const size_t off = (size_t)row * N + col;
  if (EPI == 1) {
    ((float*)outv)[off] = v + res[off];
  } else if (EPI == 2) {
    const float u = 0.7978845608f * (v + 0.044715f * v * v * v);
    ((ushort*)outv)[off] = f2bf(v / (1.f + __expf(-2.f * u)));
  } else if (EPI == 3) {
    qkv_store(row, col, v, qpk, kpk, vpk);
  } else if (EPI == 4) {
    ((ushort*)outv)[off] = f2bf(v + res[off]);
  } else if (EPI == 5) {
    ((float*)outv)[off] = v + bf2f(((const ushort*)res)[off]);
  } else {
    ((ushort*)outv)[off] = f2bf(v);
  }
}

// ---------------------------------------------------------------------------
// R6/R11 GEMM (verified): counted-vmcnt half-set pipeline. Used for FFN1.
// ---------------------------------------------------------------------------
template <int BM, int EPI>
__global__ __launch_bounds__(512, 2) void gemm8p_kernel(
    const ushort* __restrict__ A, const ushort* __restrict__ BT,
    const float* __restrict__ bias, const float* __restrict__ res,
    void* __restrict__ outv,
    ushort* __restrict__ qpk, ushort* __restrict__ kpk, ushort* __restrict__ vpk,
    int M, int N, int K) {
  constexpr int MR = BM / 32;
  constexpr int MH = BM / 64;

  __shared__ ushort lds[2 * (BM * 64 + 256 * 64)];
  char* const a0p = (char*)lds;
  char* const b0p = a0p + BM * 128;
  char* const a1p = b0p + 32768;
  char* const b1p = a1p + BM * 128;

  const int t = threadIdx.x;
  const int w = t >> 6, l = t & 63;
  const int l16 = l & 15, lg = l >> 4;
  const int lr = l >> 3, lsl = l & 7;
  const int wm = w >> 2, wn = w & 3;
  const int l7 = l & 7;

  const int nwg = gridDim.x * gridDim.y;
  const int lin = blockIdx.y * gridDim.x + blockIdx.x;
  const int work = (lin & 7) * (nwg >> 3) + (lin >> 3);
  const int bn = work % gridDim.x, bm = work / gridDim.x;
  const int tm = bm * BM, tn = bn * 256;

  const int xk0 = (lg ^ l7) << 4;
  const int xk1 = ((lg + 4) ^ l7) << 4;
  const int aoff = (wm * (BM / 2) + l16) * 128;
  const int boff = (wn * 64 + l16) * 128;
  const char* rA0k0 = a0p + aoff + xk0;  const char* rA0k1 = a0p + aoff + xk1;
  const char* rA1k0 = a1p + aoff + xk0;  const char* rA1k1 = a1p + aoff + xk1;
  const char* rB0k0 = b0p + boff + xk0;  const char* rB0k1 = b0p + boff + xk1;
  const char* rB1k0 = b1p + boff + xk0;  const char* rB1k1 = b1p + boff + xk1;

  int rA00, rA01, rA10, rA11;
  if (BM == 256) {
    rA00 = 0 * 128 + 0 * 64 + w * 8 + lr;  rA01 = 1 * 128 + 0 * 64 + w * 8 + lr;
    rA10 = 0 * 128 + 1 * 64 + w * 8 + lr;  rA11 = 1 * 128 + 1 * 64 + w * 8 + lr;
  } else {
    const int ri = w * 8 + lr;
    rA00 = (ri >> 5) * 64 + 0 * 32 + (ri & 31);
    rA10 = (ri >> 5) * 64 + 1 * 32 + (ri & 31);
    rA01 = rA00; rA11 = rA10;
  }
  const int riB0 = w * 8 + lr, riB1 = 64 + w * 8 + lr;
  const int rB00 = (riB0 >> 5) * 64 + (riB0 & 31);
  const int rB01 = (riB1 >> 5) * 64 + (riB1 & 31);
  const int rB10 = (riB0 >> 5) * 64 + 32 + (riB0 & 31);
  const int rB11 = (riB1 >> 5) * 64 + 32 + (riB1 & 31);
  const int gcol = (lsl ^ lr) << 3;
  const ushort* pa00 = A + (size_t)(tm + rA00) * K + gcol;
  const ushort* pa01 = A + (size_t)(tm + rA01) * K + gcol;
  const ushort* pa10 = A + (size_t)(tm + rA10) * K + gcol;
  const ushort* pa11 = A + (size_t)(tm + rA11) * K + gcol;
  const ushort* pb00 = BT + (size_t)(tn + rB00) * K + gcol;
  const ushort* pb01 = BT + (size_t)(tn + rB01) * K + gcol;
  const ushort* pb10 = BT + (size_t)(tn + rB10) * K + gcol;
  const ushort* pb11 = BT + (size_t)(tn + rB11) * K + gcol;
  const int da00 = rA00 * 128 + lsl * 16, da01 = rA01 * 128 + lsl * 16;
  const int da10 = rA10 * 128 + lsl * 16, da11 = rA11 * 128 + lsl * 16;
  const int db00 = rB00 * 128 + lsl * 16, db01 = rB01 * 128 + lsl * 16;
  const int db10 = rB10 * 128 + lsl * 16, db11 = rB11 * 128 + lsl * 16;

  const f32x4 z4 = {0.f, 0.f, 0.f, 0.f};
  f32x4 acc[MR][4];
#pragma unroll
  for (int i = 0; i < MR; ++i)
#pragma unroll
    for (int j = 0; j < 4; ++j) acc[i][j] = z4;

  auto ktile = [&](const char* rAk0, const char* rAk1,
                   const char* rBk0, const char* rBk1,
                   char* NA, char* NB, int ktn, bool dost) {
    bf16x8 af[MH][2], bfr[2][2];
#pragma unroll
    for (int q = 0; q < 4; ++q) {
      const int mh = q >> 1, nh = q & 1;
      if ((q & 1) == 0) {
#pragma unroll
        for (int mi = 0; mi < MH; ++mi) {
          af[mi][0] = *(const bf16x8*)(rAk0 + mh * (BM / 4) * 128 + mi * 2048);
          af[mi][1] = *(const bf16x8*)(rAk1 + mh * (BM / 4) * 128 + mi * 2048);
        }
      }
#pragma unroll
      for (int ni = 0; ni < 2; ++ni) {
        bfr[ni][0] = *(const bf16x8*)(rBk0 + nh * 4096 + ni * 2048);
        bfr[ni][1] = *(const bf16x8*)(rBk1 + nh * 4096 + ni * 2048);
      }
      if (dost && q < 2) {
        if (q == 0) {
          gload16(pa00 + ktn, NA + da00);
          if (BM == 256) gload16(pa01 + ktn, NA + da01);
          gload16(pb00 + ktn, NB + db00);
          gload16(pb01 + ktn, NB + db01);
        } else {
          gload16(pa10 + ktn, NA + da10);
          if (BM == 256) gload16(pa11 + ktn, NA + da11);
          gload16(pb10 + ktn, NB + db10);
          gload16(pb11 + ktn, NB + db11);
        }
      }
      if (q == 0) {
        if (dost) { if (BM == 256) VMCNT(4); else VMCNT(3); }
        else VMCNT(0);
      }
      if (q == 3 && dost) { if (BM == 256) VMCNT(4); else VMCNT(3); }
      __builtin_amdgcn_s_barrier();
      asm volatile("s_waitcnt lgkmcnt(0)" ::: "memory");
      SB0();
      __builtin_amdgcn_s_setprio(1);
#pragma unroll
      for (int mi = 0; mi < MH; ++mi)
#pragma unroll
        for (int ni = 0; ni < 2; ++ni)
#pragma unroll
          for (int ks = 0; ks < 2; ++ks)
            acc[mh * MH + mi][nh * 2 + ni] = __builtin_amdgcn_mfma_f32_16x16x32_bf16(
                af[mi][ks], bfr[ni][ks], acc[mh * MH + mi][nh * 2 + ni], 0, 0, 0);
      __builtin_amdgcn_s_setprio(0);
    }
  };

  gload16(pa00, a0p + da00);
  if (BM == 256) gload16(pa01, a0p + da01);
  gload16(pb00, b0p + db00);
  gload16(pb01, b0p + db01);
  gload16(pa10, a0p + da10);
  if (BM == 256) gload16(pa11, a0p + da11);
  gload16(pb10, b0p + db10);
  gload16(pb11, b0p + db11);
  VMCNT(0);
  __builtin_amdgcn_s_barrier();

  const int nt = K >> 6;
  for (int it = 0; it < nt; it += 2) {
    ktile(rA0k0, rA0k1, rB0k0, rB0k1, a1p, b1p, (it + 1) << 6, true);
    ktile(rA1k0, rA1k1, rB1k0, rB1k1, a0p, b0p, (it + 2) << 6, (it + 2) < nt);
  }

  const int row0 = tm + wm * (BM / 2) + lg * 4;
  const int col0 = tn + wn * 64 + l16;
#pragma unroll
  for (int ni = 0; ni < 4; ++ni) {
    const int col = col0 + ni * 16;
    const float bvl = bias[col];
#pragma unroll
    for (int mi = 0; mi < MR; ++mi) {
#pragma unroll
      for (int r = 0; r < 4; ++r) {
        const int row = row0 + mi * 16 + r;
        epi_store<EPI>(outv, res, qpk, kpk, vpk, row, col, N, acc[mi][ni][r] + bvl);
      }
    }
  }
}

// ---------------------------------------------------------------------------
// R13 3-deep buffer rotation GEMM, BM=128, BN=256, BK=64, 512 thr.
// ---------------------------------------------------------------------------
#define G3BODY(CB, SB)                                                         \
  {                                                                            \
    const bool s2_ = (tt + 2) < nt;                                            \
    if (s2_) {                                                                 \
      const int k2_ = (tt + 2) << 6;                                           \
      gload16(ga0 + k2_, Ab##SB + da0); gload16(ga1 + k2_, Ab##SB + da1);      \
      gload16(gb0 + k2_, Bb##SB + db0); gload16(gb1 + k2_, Bb##SB + db1);      \
      gload16(gb2 + k2_, Bb##SB + db2); gload16(gb3 + k2_, Bb##SB + db3);      \
    }                                                                          \
    bf16x8 af_[4][2], bf_[4][2];                                               \
    _Pragma("unroll") for (int mf = 0; mf < 4; ++mf) {                         \
      af_[mf][0] = *(const bf16x8*)(pA##CB##0 + mf * 2048);                    \
      af_[mf][1] = *(const bf16x8*)(pA##CB##1 + mf * 2048);                    \
    }                                                                          \
    _Pragma("unroll") for (int nf = 0; nf < 4; ++nf) {                         \
      bf_[nf][0] = *(const bf16x8*)(pB##CB##0 + nf * 2048);                    \
      bf_[nf][1] = *(const bf16x8*)(pB##CB##1 + nf * 2048);                    \
    }                                                                          \
    __builtin_amdgcn_s_setprio(1);                                             \
    _Pragma("unroll") for (int mf = 0; mf < 4; ++mf)                           \
      _Pragma("unroll") for (int nf = 0; nf < 4; ++nf)                         \
        _Pragma("unroll") for (int ks = 0; ks < 2; ++ks)                       \
          acc[mf][nf] = __builtin_amdgcn_mfma_f32_16x16x32_bf16(               \
              af_[mf][ks], bf_[nf][ks], acc[mf][nf], 0, 0, 0);                 \
    __builtin_amdgcn_s_setprio(0);                                             \
    asm volatile("s_waitcnt lgkmcnt(0)" ::: "memory");                         \
    if (s2_) { VMCNT(6); }                                                     \
    else if (tt + 1 < nt) { VMCNT(0); }                                        \
    __builtin_amdgcn_s_barrier();                                              \
  }

template <int EPI>
__global__ __launch_bounds__(512, 2) void gemm3b_kernel(
    const ushort* __restrict__ A, const ushort* __restrict__ BT,
    const float* __restrict__ bias, const float* __restrict__ res,
    void* __restrict__ outv,
    ushort* __restrict__ qpk, ushort* __restrict__ kpk, ushort* __restrict__ vpk,
    int M, int N, int K) {
  __shared__ ushort lds[73728];              // 144 KiB = 3 x (16KB A + 32KB B)
  char* const L = (char*)lds;
  char* const Ab0 = L;             char* const Bb0 = L + 16384;
  char* const Ab1 = L + 49152;     char* const Bb1 = Ab1 + 16384;
  char* const Ab2 = L + 98304;     char* const Bb2 = Ab2 + 16384;

  const int t = threadIdx.x;
  const int w = t >> 6, l = t & 63;
  const int l16 = l & 15, lg = l >> 4, lr = l >> 3, lsl = l & 7, l7 = l & 7;
  const int wm = w >> 2, wn = w & 3;

  const int nwg = gridDim.x * gridDim.y;
  const int lin = blockIdx.y * gridDim.x + blockIdx.x;
  const int work = (lin & 7) * (nwg >> 3) + (lin >> 3);
  const int bn = work % gridDim.x, bm = work / gridDim.x;
  const int tm = bm * 128, tn = bn * 256;

  const int xk0 = (lg ^ l7) << 4, xk1 = ((4 + lg) ^ l7) << 4;
  const int aoff = (wm * 64 + l16) * 128;
  const int boff = (wn * 64 + l16) * 128;
  const char* pA00 = Ab0 + aoff + xk0;  const char* pA01 = Ab0 + aoff + xk1;
  const char* pA10 = Ab1 + aoff + xk0;  const char* pA11 = Ab1 + aoff + xk1;
  const char* pA20 = Ab2 + aoff + xk0;  const char* pA21 = Ab2 + aoff + xk1;
  const char* pB00 = Bb0 + boff + xk0;  const char* pB01 = Bb0 + boff + xk1;
  const char* pB10 = Bb1 + boff + xk0;  const char* pB11 = Bb1 + boff + xk1;
  const char* pB20 = Bb2 + boff + xk0;  const char* pB21 = Bb2 + boff + xk1;

  const int ri = w * 8 + lr;
  const int rA0 = (ri >> 5) * 64 + (ri & 31);
  const int rA1 = rA0 + 32;
  const int ri2 = 64 + ri;
  const int rB0 = rA0;
  const int rB1 = (ri2 >> 5) * 64 + (ri2 & 31);
  const int rB2 = rB0 + 32;
  const int rB3 = rB1 + 32;
  const int gcol = (lsl ^ lr) << 3;
  const ushort* ga0 = A + (size_t)(tm + rA0) * K + gcol;
  const ushort* ga1 = A + (size_t)(tm + rA1) * K + gcol;
  const ushort* gb0 = BT + (size_t)(tn + rB0) * K + gcol;
  const ushort* gb1 = BT + (size_t)(tn + rB1) * K + gcol;
  const ushort* gb2 = BT + (size_t)(tn + rB2) * K + gcol;
  const ushort* gb3 = BT + (size_t)(tn + rB3) * K + gcol;
  const int da0 = rA0 * 128 + lsl * 16, da1 = rA1 * 128 + lsl * 16;
  const int db0 = rB0 * 128 + lsl * 16, db1 = rB1 * 128 + lsl * 16;
  const int db2 = rB2 * 128 + lsl * 16, db3 = rB3 * 128 + lsl * 16;

  const f32x4 z4 = {0.f, 0.f, 0.f, 0.f};
  f32x4 acc[4][4];
#pragma unroll
  for (int i = 0; i < 4; ++i)
#pragma unroll
    for (int j = 0; j < 4; ++j) acc[i][j] = z4;

  const int nt = K >> 6;

  gload16(ga0, Ab0 + da0); gload16(ga1, Ab0 + da1);
  gload16(gb0, Bb0 + db0); gload16(gb1, Bb0 + db1);
  gload16(gb2, Bb0 + db2); gload16(gb3, Bb0 + db3);
  gload16(ga0 + 64, Ab1 + da0); gload16(ga1 + 64, Ab1 + da1);
  gload16(gb0 + 64, Bb1 + db0); gload16(gb1 + 64, Bb1 + db1);
  gload16(gb2 + 64, Bb1 + db2); gload16(gb3 + 64, Bb1 + db3);
  VMCNT(6);
  __builtin_amdgcn_s_barrier();

  int tt = 0;
  while (true) {
    G3BODY(0, 2); ++tt; if (tt >= nt) break;
    G3BODY(1, 0); ++tt; if (tt >= nt) break;
    G3BODY(2, 1); ++tt; if (tt >= nt) break;
  }

  const int row0 = tm + wm * 64 + lg * 4;
  const int col0 = tn + wn * 64 + l16;
#pragma unroll
  for (int ni = 0; ni < 4; ++ni) {
    const int col = col0 + ni * 16;
    const float bvl = bias[col];
#pragma unroll
    for (int mi = 0; mi < 4; ++mi) {
#pragma unroll
      for (int r = 0; r < 4; ++r) {
        const int row = row0 + mi * 16 + r;
        epi_store<EPI>(outv, res, qpk, kpk, vpk, row, col, N, acc[mi][ni][r] + bvl);
      }
    }
  }
}

// ---------------------------------------------------------------------------
// Flash attention: zero-LDS, all operands fragment-packed & coalesced.
// ---------------------------------------------------------------------------
__global__ __launch_bounds__(256) void attn_kernel(const ushort* __restrict__ qpk,
                                                   const ushort* __restrict__ kpk,
                                                   const ushort* __restrict__ vpk,
                                                   ushort* __restrict__ ctx) {
  const int lin = blockIdx.x + blockIdx.y * gridDim.x;
  const int work = (lin & 7) * 128 + (lin >> 3);
  const int qt = work & 15, bh = work >> 4;
  const int b = bh >> 5, h = bh & 31;
  const int t = threadIdx.x, w = t >> 6, l = t & 63;
  const int l32 = l & 31, hi = l >> 5;

  const ushort* qb = qpk + ((((size_t)bh * 64 + qt * 4 + w) * 4) * 64 + l) * 8;
  bf16x8 qf0 = *(const bf16x8*)(qb);
  bf16x8 qf1 = *(const bf16x8*)(qb + 512);
  bf16x8 qf2 = *(const bf16x8*)(qb + 1024);
  bf16x8 qf3 = *(const bf16x8*)(qb + 1536);

  const ushort* kbase = kpk + (size_t)bh * 131072 + l * 8;
  const ushort* vbase = vpk + (size_t)bh * 131072 + l * 8;

  f32x16 oacc0, oacc1;
#pragma unroll
  for (int r = 0; r < 16; ++r) { oacc0[r] = 0.f; oacc1[r] = 0.f; }
  float m = -1e30f, lsum = 0.f;
  const f32x16 z16 = {};

#define LOADK(k0, k1, k2, k3, kt) {                                           \
    const ushort* p_ = kbase + (size_t)(kt) * 2048;                           \
    k0 = *(const bf16x8*)(p_);        k1 = *(const bf16x8*)(p_ + 512);        \
    k2 = *(const bf16x8*)(p_ + 1024); k3 = *(const bf16x8*)(p_ + 1536); }
#define LOADV(v0, v1, v2, v3, kt) {                                           \
    const ushort* p_ = vbase + (size_t)(kt) * 2048;                           \
    v0 = *(const bf16x8*)(p_);        v1 = *(const bf16x8*)(p_ + 512);        \
    v2 = *(const bf16x8*)(p_ + 1024); v3 = *(const bf16x8*)(p_ + 1536); }

#define STEP(k0, k1, k2, k3, v0, v1, v2, v3) {                                \
    f32x16 s = __builtin_amdgcn_mfma_f32_32x32x16_bf16(k0, qf0, z16, 0, 0, 0);\
    s = __builtin_amdgcn_mfma_f32_32x32x16_bf16(k1, qf1, s, 0, 0, 0);         \
    s = __builtin_amdgcn_mfma_f32_32x32x16_bf16(k2, qf2, s, 0, 0, 0);         \
    s = __builtin_amdgcn_mfma_f32_32x32x16_bf16(k3, qf3, s, 0, 0, 0);         \
    float tm_ = s[0];                                                         \
    _Pragma("unroll") for (int r = 1; r < 16; ++r) tm_ = fmaxf(tm_, s[r]);    \
    tm_ = fmaxf(tm_, __shfl_xor(tm_, 32));                                    \
    if (!__all(tm_ - m <= 8.f)) {                                             \
      const float mn = fmaxf(m, tm_);                                         \
      const float sf = EXP2(m - mn);                                          \
      m = mn;                                                                 \
      lsum *= sf;                                                             \
      _Pragma("unroll") for (int r = 0; r < 16; ++r) {                        \
        const float f = __shfl(sf, (r & 3) + 8 * (r >> 2) + 4 * hi);          \
        oacc0[r] *= f; oacc1[r] *= f;                                         \
      }                                                                       \
    }                                                                         \
    float p[16];                                                              \
    _Pragma("unroll") for (int r = 0; r < 16; ++r) p[r] = EXP2(s[r] - m);     \
    float ls = 0.f;                                                           \
    _Pragma("unroll") for (int r = 0; r < 16; ++r) ls += p[r];                \
    lsum += ls;                                                               \
    unsigned pw[8];                                                           \
    _Pragma("unroll") for (int i = 0; i < 8; ++i)                             \
      asm("v_cvt_pk_bf16_f32 %0, %1, %2" : "=v"(pw[i]) : "v"(p[2*i]), "v"(p[2*i+1])); \
    unsigned a0 = pw[0], b0 = pw[2];                                          \
    asm("v_permlane32_swap_b32 %0, %1" : "+v"(a0), "+v"(b0));                 \
    unsigned a1 = pw[1], b1 = pw[3];                                          \
    asm("v_permlane32_swap_b32 %0, %1" : "+v"(a1), "+v"(b1));                 \
    unsigned a2 = pw[4], b2 = pw[6];                                          \
    asm("v_permlane32_swap_b32 %0, %1" : "+v"(a2), "+v"(b2));                 \
    unsigned a3 = pw[5], b3 = pw[7];                                          \
    asm("v_permlane32_swap_b32 %0, %1" : "+v"(a3), "+v"(b3));                 \
    union { unsigned uw[4]; bf16x8 v; } pa0, pa1;                             \
    pa0.uw[0] = a0; pa0.uw[1] = a1; pa0.uw[2] = b0; pa0.uw[3] = b1;           \
    pa1.uw[0] = a2; pa1.uw[1] = a3; pa1.uw[2] = b2; pa1.uw[3] = b3;           \
    oacc0 = __builtin_amdgcn_mfma_f32_32x32x16_bf16(pa0.v, v0, oacc0, 0, 0, 0);\
    oacc1 = __builtin_amdgcn_mfma_f32_32x32x16_bf16(pa0.v, v1, oacc1, 0, 0, 0);\
    oacc0 = __builtin_amdgcn_mfma_f32_32x32x16_bf16(pa1.v, v2, oacc0, 0, 0, 0);\
    oacc1 = __builtin_amdgcn_mfma_f32_32x32x16_bf16(pa1.v, v3, oacc1, 0, 0, 0);}

  bf16x8 ka0, ka1, ka2, ka3, kc0, kc1, kc2, kc3;
  LOADK(ka0, ka1, ka2, ka3, 0);
  for (int kt = 0; kt < 64; kt += 2) {
    bf16x8 va0, va1, va2, va3;
    LOADV(va0, va1, va2, va3, kt);
    LOADK(kc0, kc1, kc2, kc3, kt + 1);
    STEP(ka0, ka1, ka2, ka3, va0, va1, va2, va3);
    LOADV(va0, va1, va2, va3, kt + 1);
    if (kt + 2 < 64) LOADK(ka0, ka1, ka2, ka3, kt + 2);
    STEP(kc0, kc1, kc2, kc3, va0, va1, va2, va3);
  }
#undef LOADK
#undef LOADV
#undef STEP

  const float lf = lsum + __shfl_xor(lsum, 32);
  const float linv = 1.f / lf;
#pragma unroll
  for (int r = 0; r < 16; ++r) {
    const int qr = (r & 3) + 8 * (r >> 2);
    const float fac = __shfl(linv, qr + 4 * hi);
    const int row = qt * 128 + w * 32 + qr + 4 * hi;
    const size_t base = ((size_t)(b * SEQ + row)) * HID + h * 64 + l32;
    ctx[base]      = f2bf(oacc0[r] * fac);
    ctx[base + 32] = f2bf(oacc1[r] * fac);
  }
}

// ---------------------------------------------------------------------------
extern "C" void kernel_launch(void* const* d_in, const int* in_sizes, int n_in,
                              void* d_out, int out_size, void* d_ws, size_t ws_size,
                              hipStream_t stream) {
  const float* x      = (const float*)d_in[0];
  const float* ln1g   = (const float*)d_in[1];
  const float* ln1b   = (const float*)d_in[2];
  const float* w_qkv  = (const float*)d_in[3];
  const float* b_qkv  = (const float*)d_in[4];
  const float* w_proj = (const float*)d_in[5];
  const float* b_proj = (const float*)d_in[6];
  const float* ln2g   = (const float*)d_in[7];
  const float* ln2b   = (const float*)d_in[8];
  const float* w1     = (const float*)d_in[9];
  const float* b1     = (const float*)d_in[10];
  const float* w2     = (const float*)d_in[11];
  const float* b2     = (const float*)d_in[12];

  char* ws = (char*)d_ws;
  ushort* wqkvT  = (ushort*)(ws + 0);             // [6144][2048] bf16  24MB
  ushort* wprojT = (ushort*)(ws + 25165824);      // [2048][2048] bf16   8MB
  ushort* w1T    = (ushort*)(ws + 33554432);      // [8192][2048] bf16  32MB
  ushort* w2T    = (ushort*)(ws + 67108864);      // [2048][8192] bf16  32MB
  ushort* hbuf   = (ushort*)(ws + 100663296);     // [4096][2048] bf16  16MB (LN1/LN2 out)
  ushort* qpk    = (ushort*)(ws + 117440512);     // packed Q 16MB
  ushort* kpk    = (ushort*)(ws + 134217728);     // packed K 16MB
  ushort* vpk    = (ushort*)(ws + 150994944);     // packed V 16MB
  ushort* ctxb   = (ushort*)(ws + 167772160);     // [4096][2048] bf16  16MB
  ushort* gelu   = (ushort*)(ws + 117440512);     // [4096][8192] bf16  64MB (reuses q/k/v/ctx)
  ushort* x2bf   = (ushort*)(ws + 184549376);     // [4096][2048] bf16  16MB

  // all four weight transposes in ONE launch (12288 blocks)
  tcvt_all_kernel<<<12288, 256, 0, stream>>>(w_qkv, w_proj, w1, w2,
                                             wqkvT, wprojT, w1T, w2T);

  // LN1 -> hbuf (bf16)
  ln_kernel<<<NTOK, 256, 0, stream>>>(x, ln1g, ln1b, hbuf);
  // QKV = h @ w_qkv + b_qkv, fragment-packed out. grid 24x32 = 768
  gemm3b_kernel<3><<<dim3(24, 32), 512, 0, stream>>>(
      hbuf, wqkvT, b_qkv, nullptr, nullptr, qpk, kpk, vpk, NTOK, QKVW, HID);
  // attention -> ctxb (bf16)
  attn_kernel<<<dim3(16, 2 * NHEAD), 256, 0, stream>>>(qpk, kpk, vpk, ctxb);
  // x2 = ctx @ w_proj + b_proj + x  -> bf16. grid 8x32 = 256
  gemm3b_kernel<4><<<dim3(8, 32), 512, 0, stream>>>(
      ctxb, wprojT, b_proj, x, x2bf, nullptr, nullptr, nullptr, NTOK, HID, HID);
  // LN2 (bf16 input) -> hbuf
  ln_bf_kernel<<<NTOK, 256, 0, stream>>>(x2bf, ln2g, ln2b, hbuf);
  // g = gelu(h @ w1 + b1). gemm8p BM=256, grid 32x16 = 512 (verified best)
  gemm8p_kernel<256, 2><<<dim3(32, 16), 512, 0, stream>>>(
      hbuf, w1T, b1, nullptr, gelu, nullptr, nullptr, nullptr, NTOK, NFFN, HID);
  // out = g @ w2 + b2 + x2(bf16 res) -> f32. grid 8x32 = 256
  gemm3b_kernel<5><<<dim3(8, 32), 512, 0, stream>>>(
      gelu, w2T, b2, (const float*)x2bf, (float*)d_out, nullptr, nullptr, nullptr,
      NTOK, HID, NFFN);
}